// Round 5
// baseline (1845.619 us; speedup 1.0000x reference)
//
#include <hip/hip_runtime.h>
#include <math.h>

#define T_STEPS 4
#define NNODES 50000
#define NEDGES 400000
#define FIN 128   // input feature dim for both layers
#define NBINS 8192
#define BINSHIFT 19  // 32-13

__device__ __forceinline__ float sigmoidf_(float x) { return 1.0f / (1.0f + __expf(-x)); }

__device__ __forceinline__ unsigned int key_of(float s) {
    unsigned int u = __float_as_uint(s);
    return (u & 0x80000000u) ? ~u : (u | 0x80000000u);
}

__device__ __forceinline__ unsigned short f2bf(float f) {
    unsigned int u = __float_as_uint(f);
    unsigned int r = (u + 0x7FFFu + ((u >> 16) & 1u)) >> 16;
    return (unsigned short)r;
}
__device__ __forceinline__ float bf2f(unsigned short h) {
    return __uint_as_float(((unsigned int)h) << 16);
}

// ---------------- norms of the two scorers ----------------
__global__ void norm_kernel(const float* __restrict__ s0, const float* __restrict__ s1,
                            float* __restrict__ norms) {
    __shared__ float red[128];
    int tid = threadIdx.x;  // 128 threads
    float a = s0[tid];
    red[tid] = a * a;
    __syncthreads();
    for (int off = 64; off > 0; off >>= 1) { if (tid < off) red[tid] += red[tid + off]; __syncthreads(); }
    if (tid == 0) norms[0] = sqrtf(red[0]);
    __syncthreads();
    float b = s1[tid];
    red[tid] = b * b;
    __syncthreads();
    for (int off = 64; off > 0; off >>= 1) { if (tid < off) red[tid] += red[tid + off]; __syncthreads(); }
    if (tid == 0) norms[1] = sqrtf(red[0]);
}

// ---------------- L0: scores = X @ scorer / norm + mask, fused topk histogram ----------------
__global__ void scores_hist_kernel(const float* __restrict__ X, const float* __restrict__ scorer,
                                   const float* __restrict__ norms, int normIdx,
                                   const float* __restrict__ mask, float* __restrict__ scores,
                                   int* __restrict__ ghist, int N) {
    __shared__ float sc[FIN];
    if (threadIdx.x < FIN) sc[threadIdx.x] = scorer[threadIdx.x];
    __syncthreads();
    int n = blockIdx.x * blockDim.x + threadIdx.x;
    if (n >= N) return;
    const float4* xr = (const float4*)(X + (size_t)n * FIN);
    float acc = 0.f;
#pragma unroll 8
    for (int k4 = 0; k4 < FIN / 4; k4++) {
        float4 v = xr[k4];
        acc += v.x * sc[k4 * 4] + v.y * sc[k4 * 4 + 1] + v.z * sc[k4 * 4 + 2] + v.w * sc[k4 * 4 + 3];
    }
    float s = acc / norms[normIdx] + mask[n];
    scores[n] = s;
    atomicAdd(&ghist[key_of(s) >> BINSHIFT], 1);
}

// ---------------- find critical bin; self-zero ghist+cnts for next use ----------------
__global__ void __launch_bounds__(1024)
topk_findbin_kernel(int* __restrict__ ghist, int* __restrict__ cnts, int* __restrict__ meta, int K) {
    __shared__ int h[NBINS];
    __shared__ int cs[1024];
    int tid = threadIdx.x;
    for (int i = tid; i < NBINS; i += 1024) h[i] = ghist[i];
    __syncthreads();
    int s = 0;
#pragma unroll
    for (int i = 0; i < NBINS / 1024; i++) s += h[tid * (NBINS / 1024) + i];
    cs[tid] = s;
    __syncthreads();
    for (int off = 1; off < 1024; off <<= 1) {
        int v = (tid + off < 1024) ? cs[tid + off] : 0;
        __syncthreads();
        cs[tid] += v;
        __syncthreads();
    }
    int run = (tid == 1023) ? 0 : cs[tid + 1];  // S(chunk_end)
    const int CH = NBINS / 1024;
    for (int b = tid * CH + CH - 1; b >= tid * CH; b--) {
        int Sb = run + h[b];
        if (Sb >= K && run < K) { meta[0] = b; meta[1] = K - run; }
        run = Sb;
    }
    // zero for the next histogram user (values already staged into LDS)
    for (int i = tid; i < NBINS; i += 1024) ghist[i] = 0;
    if (tid == 0) { cnts[0] = 0; cnts[1] = 0; }
}

// ---------------- collect candidates ----------------
__global__ void topk_collect_kernel(const float* __restrict__ scores, const int* __restrict__ meta,
                                    int* __restrict__ cnts, int* __restrict__ gt_idx,
                                    float* __restrict__ gt_val, int* __restrict__ eq_idx,
                                    float* __restrict__ eq_val, int N) {
    int n = blockIdx.x * blockDim.x + threadIdx.x;
    if (n >= N) return;
    float sc = scores[n];
    int key = (int)(key_of(sc) >> BINSHIFT);
    int b = meta[0];
    if (key > b) {
        int p = atomicAdd(&cnts[0], 1);
        gt_idx[p] = n; gt_val[p] = sc;
    } else if (key == b) {
        int p = atomicAdd(&cnts[1], 1);
        eq_idx[p] = n; eq_val[p] = sc;
    }
}

// ---------------- finish: exact top-K (ties -> lower idx) + build z in-place ----------------
// z[r*K + j] = X[idx_j*FIN + r] * tanh(val_j)
#define EQLDS 2048
template <int K>
__global__ void __launch_bounds__(1024)
topk_finish_kernel(const int* __restrict__ meta, const int* __restrict__ cnts,
                   const int* __restrict__ gt_idx, const float* __restrict__ gt_val,
                   const int* __restrict__ eq_idx, const float* __restrict__ eq_val,
                   const float* __restrict__ X, float* __restrict__ z) {
    __shared__ int sidx[K];
    __shared__ float sval[K];
    __shared__ unsigned int ek[EQLDS];
    __shared__ int ei[EQLDS];
    __shared__ int out_idx[K];
    __shared__ float out_tanh[K];
    int tid = threadIdx.x;
    int g = cnts[0];
    int m = cnts[1];
    int need = meta[1];
    for (int i = tid; i < g; i += 1024) { sidx[i] = gt_idx[i]; sval[i] = gt_val[i]; }
    bool use_lds = (m <= EQLDS);
    if (use_lds) {
        for (int i = tid; i < m; i += 1024) { ek[i] = key_of(eq_val[i]); ei[i] = eq_idx[i]; }
    }
    __syncthreads();
    for (int i = tid; i < m; i += 1024) {
        int myi = eq_idx[i];
        unsigned int myk = key_of(eq_val[i]);
        int rank = 0;
        if (use_lds) {
            for (int j = 0; j < m; j++)
                rank += (ek[j] > myk) || (ek[j] == myk && ei[j] < myi);
        } else {
            for (int j = 0; j < m; j++) {
                unsigned int kj = key_of(eq_val[j]);
                rank += (kj > myk) || (kj == myk && eq_idx[j] < myi);
            }
        }
        if (rank < need) { sidx[g + rank] = myi; sval[g + rank] = eq_val[i]; }
    }
    __syncthreads();
    if (tid < K) {
        float v = sval[tid];
        int id = sidx[tid];
        unsigned int myk = key_of(v);
        int rank = 0;
        for (int j = 0; j < K; j++) {
            unsigned int kj = key_of(sval[j]);
            rank += (kj > myk) || (kj == myk && sidx[j] < id);
        }
        out_idx[rank] = id;
        out_tanh[rank] = tanhf(v);
    }
    __syncthreads();
    // z build: read-coalesced (r fastest within each selected row)
    for (int i = tid; i < K * FIN; i += 1024) {
        int j = i >> 7;        // / FIN
        int r = i & 127;       // % FIN
        z[r * K + j] = X[(size_t)out_idx[j] * FIN + r] * out_tanh[j];
    }
}

// ---------------- fused GRU: upd/rst/hcap/Qn in one kernel ----------------
// block owns 8 full columns: rst*Q is block-local in LDS
template <int COLS>
__global__ void __launch_bounds__(256)
gru_fused_kernel(const float* __restrict__ z, const float* __restrict__ Q,
                 const float* __restrict__ Wu, const float* __restrict__ Uu, const float* __restrict__ Bu,
                 const float* __restrict__ Wr, const float* __restrict__ Ur, const float* __restrict__ Br,
                 const float* __restrict__ Wh, const float* __restrict__ Uh, const float* __restrict__ Bh,
                 float* __restrict__ Qn) {
    __shared__ float zc[128][8];
    __shared__ float qc[128][8];
    __shared__ float rq[128][8];
    __shared__ float ul[128][8];
    int tid = threadIdx.x;
    int c0 = blockIdx.x * 8;
    for (int i = tid; i < 1024; i += 256) {
        int r = i >> 3, c = i & 7;
        zc[r][c] = z[r * COLS + c0 + c];
        qc[r][c] = Q[r * COLS + c0 + c];
    }
    __syncthreads();
#pragma unroll
    for (int e = 0; e < 4; e++) {
        int idx = tid + 256 * e;
        int r = idx >> 3, c = idx & 7;
        float au = Bu[r * COLS + c0 + c], ar = Br[r * COLS + c0 + c];
        for (int k = 0; k < 128; k++) {
            float zz = zc[k][c], qq = qc[k][c];
            au += Wu[r * 128 + k] * zz + Uu[r * 128 + k] * qq;
            ar += Wr[r * 128 + k] * zz + Ur[r * 128 + k] * qq;
        }
        ul[r][c] = sigmoidf_(au);
        rq[r][c] = sigmoidf_(ar) * qc[r][c];
    }
    __syncthreads();
#pragma unroll
    for (int e = 0; e < 4; e++) {
        int idx = tid + 256 * e;
        int r = idx >> 3, c = idx & 7;
        float s = Bh[r * COLS + c0 + c];
        for (int k = 0; k < 128; k++) {
            s += Wh[r * 128 + k] * zc[k][c] + Uh[r * 128 + k] * rq[k][c];
        }
        float h = tanhf(s);
        float u = ul[r][c];
        Qn[r * COLS + c0 + c] = (1.f - u) * qc[r][c] + u * h;
    }
}

// ---------------- XW = X @ Qn -> fp32 or bf16 out ----------------
// BF16 only safe when nothing downstream does top-k selection on this path.
template <int COLS, bool BF16>
__global__ void __launch_bounds__(256)
xw_kernel(const float* __restrict__ X, const float* __restrict__ Qn,
          void* __restrict__ outp, int N) {
    constexpr int TPR = COLS / 4;       // threads per row (32 or 16)
    constexpr int RPG = 256 / TPR;      // rows per group (8 or 16)
    constexpr int RPB = RPG * 4;        // rows per block (32 or 64)
    __shared__ float4 qs[128 * TPR];
    for (int i = threadIdx.x; i < 128 * TPR; i += 256) qs[i] = ((const float4*)Qn)[i];
    __syncthreads();
    int lane_c = threadIdx.x % TPR;
    int rloc = threadIdx.x / TPR;
    int base = blockIdx.x * RPB;
    int rows[4];
    float4 acc[4];
#pragma unroll
    for (int j = 0; j < 4; j++) {
        rows[j] = base + rloc + j * RPG;
        acc[j] = make_float4(0.f, 0.f, 0.f, 0.f);
    }
    int nc[4];
#pragma unroll
    for (int j = 0; j < 4; j++) nc[j] = min(rows[j], N - 1);

    for (int k4 = 0; k4 < 32; k4++) {
        float4 q0 = qs[(k4 * 4 + 0) * TPR + lane_c];
        float4 q1 = qs[(k4 * 4 + 1) * TPR + lane_c];
        float4 q2 = qs[(k4 * 4 + 2) * TPR + lane_c];
        float4 q3 = qs[(k4 * 4 + 3) * TPR + lane_c];
#pragma unroll
        for (int j = 0; j < 4; j++) {
            float4 xv = ((const float4*)(X + (size_t)nc[j] * FIN))[k4];
            acc[j].x += xv.x * q0.x + xv.y * q1.x + xv.z * q2.x + xv.w * q3.x;
            acc[j].y += xv.x * q0.y + xv.y * q1.y + xv.z * q2.y + xv.w * q3.y;
            acc[j].z += xv.x * q0.z + xv.y * q1.z + xv.z * q2.z + xv.w * q3.z;
            acc[j].w += xv.x * q0.w + xv.y * q1.w + xv.z * q2.w + xv.w * q3.w;
        }
    }
#pragma unroll
    for (int j = 0; j < 4; j++) {
        if (rows[j] < N) {
            if (BF16) {
                ushort4 o;
                o.x = f2bf(acc[j].x); o.y = f2bf(acc[j].y);
                o.z = f2bf(acc[j].z); o.w = f2bf(acc[j].w);
                ((ushort4*)((unsigned short*)outp + (size_t)rows[j] * COLS))[lane_c] = o;
            } else {
                ((float4*)((float*)outp + (size_t)rows[j] * COLS))[lane_c] = acc[j];
            }
        }
    }
}

// ---------------- batched CSR build over all 4 timesteps ----------------
__global__ void hist4_kernel(const int* __restrict__ dst, int* __restrict__ hist4, int total) {
    int gid = blockIdx.x * blockDim.x + threadIdx.x;
    if (gid >= total) return;
    int t = gid / NEDGES;
    atomicAdd(&hist4[t * NNODES + dst[gid]], 1);
}

__global__ void __launch_bounds__(256)
scanA_kernel(const int* __restrict__ hist, int* __restrict__ incl, int* __restrict__ bsum, int M) {
    __shared__ int sh[256];
    int gid = blockIdx.x * 256 + threadIdx.x;
    int v = (gid < M) ? hist[gid] : 0;
    sh[threadIdx.x] = v;
    __syncthreads();
    for (int off = 1; off < 256; off <<= 1) {
        int u = (threadIdx.x >= off) ? sh[threadIdx.x - off] : 0;
        __syncthreads();
        sh[threadIdx.x] += u;
        __syncthreads();
    }
    if (gid < M) incl[gid] = sh[threadIdx.x];
    if (threadIdx.x == 255) bsum[blockIdx.x] = sh[255];
}

__global__ void __launch_bounds__(1024)
scanB_kernel(int* __restrict__ bsum, int nb) {
    __shared__ int sh[1024];
    int tid = threadIdx.x;
    int v = (tid < nb) ? bsum[tid] : 0;
    sh[tid] = v;
    __syncthreads();
    for (int off = 1; off < 1024; off <<= 1) {
        int u = (tid >= off) ? sh[tid - off] : 0;
        __syncthreads();
        sh[tid] += u;
        __syncthreads();
    }
    if (tid < nb) bsum[tid] = (tid == 0) ? 0 : sh[tid - 1];
}

__global__ void __launch_bounds__(256)
scanC_kernel(const int* __restrict__ hist, const int* __restrict__ incl,
             const int* __restrict__ bsum, int* __restrict__ row_ptr,
             int* __restrict__ cursor, int M) {
    int gid = blockIdx.x * 256 + threadIdx.x;
    if (gid < M) {
        int inc = incl[gid] + bsum[gid / 256];
        int ex = inc - hist[gid];
        row_ptr[gid] = ex;
        cursor[gid] = ex;
        if (gid == M - 1) row_ptr[M] = inc;
    }
}

__global__ void bucket4_kernel(const int* __restrict__ src, const int* __restrict__ dst,
                               const float* __restrict__ w, int* __restrict__ cursor,
                               int* __restrict__ ssrc, float* __restrict__ sw, int total) {
    int gid = blockIdx.x * blockDim.x + threadIdx.x;
    if (gid >= total) return;
    int t = gid / NEDGES;
    int d = dst[gid];
    int pos = atomicAdd(&cursor[t * NNODES + d], 1);
    ssrc[pos] = src[gid];
    sw[pos] = w[gid];
}

// ---------------- CSR aggregation: out[d] = relu(sum w_e * XW[src_e]) ----------------
// SCORE: also compute next-layer scores = out_row @ scorer / nrm + mask, and topk histogram
template <int COLS, bool SCORE, bool BF16>
__global__ void __launch_bounds__(256)
agg_kernel(const void* __restrict__ XWp, const int* __restrict__ row_ptr,
           const int* __restrict__ ssrc, const float* __restrict__ sw,
           float* __restrict__ out, int N,
           const float* __restrict__ scorer, const float* __restrict__ norms, int normIdx,
           const float* __restrict__ mask, float* __restrict__ scores, int* __restrict__ ghist) {
    constexpr int TPN = COLS / 4;       // threads per node (32 or 16)
    constexpr int NPB = 256 / TPN;      // nodes per block (8 or 16)
    int node = blockIdx.x * NPB + threadIdx.x / TPN;
    int lane = threadIdx.x % TPN;
    if (node >= N) return;
    int beg = row_ptr[node], end = row_ptr[node + 1];
    float4 acc = make_float4(0.f, 0.f, 0.f, 0.f);
    for (int i = beg; i < end; i++) {
        int s = ssrc[i];
        float wt = sw[i];
        if (BF16) {
            ushort4 v = ((const ushort4*)((const unsigned short*)XWp + (size_t)s * COLS))[lane];
            acc.x += bf2f(v.x) * wt; acc.y += bf2f(v.y) * wt;
            acc.z += bf2f(v.z) * wt; acc.w += bf2f(v.w) * wt;
        } else {
            float4 v = ((const float4*)((const float*)XWp + (size_t)s * COLS))[lane];
            acc.x += v.x * wt; acc.y += v.y * wt; acc.z += v.z * wt; acc.w += v.w * wt;
        }
    }
    acc.x = fmaxf(acc.x, 0.f); acc.y = fmaxf(acc.y, 0.f);
    acc.z = fmaxf(acc.z, 0.f); acc.w = fmaxf(acc.w, 0.f);
    ((float4*)(out + (size_t)node * COLS))[lane] = acc;
    if (SCORE) {
        float4 sc4 = ((const float4*)scorer)[lane];
        float partial = acc.x * sc4.x + acc.y * sc4.y + acc.z * sc4.z + acc.w * sc4.w;
#pragma unroll
        for (int off = TPN / 2; off > 0; off >>= 1) partial += __shfl_xor(partial, off, TPN);
        if (lane == 0) {
            float s = partial / norms[normIdx] + mask[node];
            scores[node] = s;
            atomicAdd(&ghist[key_of(s) >> BINSHIFT], 1);
        }
    }
}

extern "C" void kernel_launch(void* const* d_in, const int* in_sizes, int n_in,
                              void* d_out, int out_size, void* d_ws, size_t ws_size,
                              hipStream_t stream) {
    const float* node_embs   = (const float*)d_in[0];
    const float* mask        = (const float*)d_in[1];
    const int*   edge_src    = (const int*)d_in[2];
    const int*   edge_dst    = (const int*)d_in[3];
    const float* edge_weight = (const float*)d_in[4];
    const float* gcn_w0      = (const float*)d_in[5];
    const float* gcn_w1      = (const float*)d_in[6];
    const float* l0p[10];
    const float* l1p[10];
    for (int i = 0; i < 10; i++) l0p[i] = (const float*)d_in[7 + i];
    for (int i = 0; i < 10; i++) l1p[i] = (const float*)d_in[17 + i];
    // l*p: 0=Wu 1=Uu 2=Bu 3=Wr 4=Ur 5=Br 6=Wh 7=Uh 8=Bh 9=scorer

    char* ws = (char*)d_ws;
    size_t off = 0;
    auto alloc = [&](size_t bytes) -> void* {
        void* p = ws + off;
        off += (bytes + 255) / 256 * 256;
        return p;
    };
    float* XWbuf  = (float*)alloc((size_t)NNODES * 128 * 4);   // fp32 L0 / bf16 L1 (reuse)
    float* h1buf  = (float*)alloc((size_t)NNODES * 128 * 4);
    float* scores = (float*)alloc((size_t)NNODES * 4);
    float* zbuf   = (float*)alloc(128 * 128 * 4);
    float* Q0a    = (float*)alloc(128 * 128 * 4);
    float* Q0b    = (float*)alloc(128 * 128 * 4);
    float* Q1a    = (float*)alloc(128 * 64 * 4);
    float* Q1b    = (float*)alloc(128 * 64 * 4);
    float* norms  = (float*)alloc(64);
    // combined zeroed region: hist4[4N] + ghist[NBINS] + cnts[pad 64]
    int* hist4    = (int*)alloc(((size_t)4 * NNODES + NBINS + 64) * 4);
    int* ghist    = hist4 + 4 * NNODES;
    int* cnts     = ghist + NBINS;
    int* incl4    = (int*)alloc((size_t)4 * NNODES * 4);
    int* bsumb    = (int*)alloc(1024 * 4);
    int* rowp4    = (int*)alloc(((size_t)4 * NNODES + 1) * 4);
    int* cursor4  = (int*)alloc((size_t)4 * NNODES * 4);
    int* ssrc4    = (int*)alloc((size_t)4 * NEDGES * 4);
    float* sww4   = (float*)alloc((size_t)4 * NEDGES * 4);
    int* meta     = (int*)alloc(64);
    int* gt_idx   = (int*)alloc(128 * 4);
    float* gt_val = (float*)alloc(128 * 4);
    int* eq_idx   = (int*)alloc((size_t)NNODES * 4);
    float* eq_val = (float*)alloc((size_t)NNODES * 4);

    hipMemcpyAsync(Q0a, gcn_w0, 128 * 128 * 4, hipMemcpyDeviceToDevice, stream);
    hipMemcpyAsync(Q1a, gcn_w1, 128 * 64 * 4, hipMemcpyDeviceToDevice, stream);
    hipMemsetAsync(hist4, 0, ((size_t)4 * NNODES + NBINS + 64) * 4, stream);
    norm_kernel<<<1, 128, 0, stream>>>(l0p[9], l1p[9], norms);

    // ---- batched CSR build for all 4 timesteps ----
    const int M4 = 4 * NNODES;
    const int NB4 = (M4 + 255) / 256;          // 782
    const int E4 = 4 * NEDGES;
    hist4_kernel<<<(E4 + 255) / 256, 256, 0, stream>>>(edge_dst, hist4, E4);
    scanA_kernel<<<NB4, 256, 0, stream>>>(hist4, incl4, bsumb, M4);
    scanB_kernel<<<1, 1024, 0, stream>>>(bsumb, NB4);
    scanC_kernel<<<NB4, 256, 0, stream>>>(hist4, incl4, bsumb, rowp4, cursor4, M4);
    bucket4_kernel<<<(E4 + 255) / 256, 256, 0, stream>>>(edge_src, edge_dst, edge_weight, cursor4, ssrc4, sww4, E4);

    float* Q0cur = Q0a; float* Q0nxt = Q0b;
    float* Q1cur = Q1a; float* Q1nxt = Q1b;
    const int NB = (NNODES + 255) / 256;       // 196

    for (int t = 0; t < T_STEPS; t++) {
        const float* X0 = node_embs + (size_t)t * NNODES * 128;
        const float* mk = mask + (size_t)t * NNODES;
        const int* rp_t = rowp4 + (size_t)t * NNODES;

        // ---- layer 0 (fp32 XW: h1 feeds layer-1 top-k selection, must stay exact) ----
        scores_hist_kernel<<<NB, 256, 0, stream>>>(X0, l0p[9], norms, 0, mk, scores, ghist, NNODES);
        topk_findbin_kernel<<<1, 1024, 0, stream>>>(ghist, cnts, meta, 128);
        topk_collect_kernel<<<NB, 256, 0, stream>>>(scores, meta, cnts, gt_idx, gt_val, eq_idx, eq_val, NNODES);
        topk_finish_kernel<128><<<1, 1024, 0, stream>>>(meta, cnts, gt_idx, gt_val, eq_idx, eq_val, X0, zbuf);
        gru_fused_kernel<128><<<16, 256, 0, stream>>>(zbuf, Q0cur,
            l0p[0], l0p[1], l0p[2], l0p[3], l0p[4], l0p[5], l0p[6], l0p[7], l0p[8], Q0nxt);
        xw_kernel<128, false><<<(NNODES + 31) / 32, 256, 0, stream>>>(X0, Q0nxt, XWbuf, NNODES);
        agg_kernel<128, true, false><<<(NNODES + 7) / 8, 256, 0, stream>>>(XWbuf, rp_t, ssrc4, sww4, h1buf, NNODES,
            l1p[9], norms, 1, mk, scores, ghist);

        // ---- layer 1 (h1buf relu'd; scores/ghist built by agg above; bf16 XW: output-only path) ----
        topk_findbin_kernel<<<1, 1024, 0, stream>>>(ghist, cnts, meta, 64);
        topk_collect_kernel<<<NB, 256, 0, stream>>>(scores, meta, cnts, gt_idx, gt_val, eq_idx, eq_val, NNODES);
        topk_finish_kernel<64><<<1, 1024, 0, stream>>>(meta, cnts, gt_idx, gt_val, eq_idx, eq_val, h1buf, zbuf);
        gru_fused_kernel<64><<<8, 256, 0, stream>>>(zbuf, Q1cur,
            l1p[0], l1p[1], l1p[2], l1p[3], l1p[4], l1p[5], l1p[6], l1p[7], l1p[8], Q1nxt);
        xw_kernel<64, true><<<(NNODES + 63) / 64, 256, 0, stream>>>(h1buf, Q1nxt, XWbuf, NNODES);
        float* out_t = (float*)d_out + (size_t)t * NNODES * 64;
        agg_kernel<64, false, true><<<(NNODES + 15) / 16, 256, 0, stream>>>(XWbuf, rp_t, ssrc4, sww4, out_t, NNODES,
            nullptr, nullptr, 0, nullptr, nullptr, nullptr);

        float* tmp;
        tmp = Q0cur; Q0cur = Q0nxt; Q0nxt = tmp;
        tmp = Q1cur; Q1cur = Q1nxt; Q1nxt = tmp;
    }
}

// Round 6
// 1705.004 us; speedup vs baseline: 1.0825x; 1.0825x over previous
//
#include <hip/hip_runtime.h>
#include <math.h>

#define T_STEPS 4
#define NNODES 50000
#define NEDGES 400000
#define FIN 128   // input feature dim for both layers
#define NBINS 8192
#define BINSHIFT 19  // 32-13
#define EQLDS 4096

__device__ __forceinline__ float sigmoidf_(float x) { return 1.0f / (1.0f + __expf(-x)); }

__device__ __forceinline__ unsigned int key_of(float s) {
    unsigned int u = __float_as_uint(s);
    return (u & 0x80000000u) ? ~u : (u | 0x80000000u);
}

__device__ __forceinline__ unsigned short f2bf(float f) {
    unsigned int u = __float_as_uint(f);
    unsigned int r = (u + 0x7FFFu + ((u >> 16) & 1u)) >> 16;
    return (unsigned short)r;
}
__device__ __forceinline__ float bf2f(unsigned short h) {
    return __uint_as_float(((unsigned int)h) << 16);
}

// ---------------- norms of the two scorers ----------------
__global__ void norm_kernel(const float* __restrict__ s0, const float* __restrict__ s1,
                            float* __restrict__ norms) {
    __shared__ float red[128];
    int tid = threadIdx.x;  // 128 threads
    float a = s0[tid];
    red[tid] = a * a;
    __syncthreads();
    for (int off = 64; off > 0; off >>= 1) { if (tid < off) red[tid] += red[tid + off]; __syncthreads(); }
    if (tid == 0) norms[0] = sqrtf(red[0]);
    __syncthreads();
    float b = s1[tid];
    red[tid] = b * b;
    __syncthreads();
    for (int off = 64; off > 0; off >>= 1) { if (tid < off) red[tid] += red[tid + off]; __syncthreads(); }
    if (tid == 0) norms[1] = sqrtf(red[0]);
}

// ---------------- L0 scores for ALL t: scores = X @ scorer / norm + mask, + topk histogram ----------------
// grid: (ceil(N/256), T_STEPS)
__global__ void scores_hist4_kernel(const float* __restrict__ node_embs, const float* __restrict__ scorer,
                                    const float* __restrict__ norms,
                                    const float* __restrict__ mask, float* __restrict__ scores4,
                                    int* __restrict__ ghist4, int N) {
    __shared__ float sc[FIN];
    if (threadIdx.x < FIN) sc[threadIdx.x] = scorer[threadIdx.x];
    __syncthreads();
    int t = blockIdx.y;
    int n = blockIdx.x * blockDim.x + threadIdx.x;
    if (n >= N) return;
    const float4* xr = (const float4*)(node_embs + ((size_t)t * N + n) * FIN);
    float acc = 0.f;
#pragma unroll 8
    for (int k4 = 0; k4 < FIN / 4; k4++) {
        float4 v = xr[k4];
        acc += v.x * sc[k4 * 4] + v.y * sc[k4 * 4 + 1] + v.z * sc[k4 * 4 + 2] + v.w * sc[k4 * 4 + 3];
    }
    float s = acc / norms[0] + mask[(size_t)t * N + n];
    scores4[(size_t)t * N + n] = s;
    atomicAdd(&ghist4[t * NBINS + (key_of(s) >> BINSHIFT)], 1);
}

// ---------------- all-in-one top-K per block: findbin + collect + exact rank + z build ----------------
// task = blockIdx.x selects which score-set/X/z slice. Ties -> lower index (matches jax.lax.top_k).
// z[r*K + j] = X[idx_j*FIN + r] * tanh(val_j). Self-zeros ghist for reuse.
template <int K>
__global__ void __launch_bounds__(1024)
topk_all_kernel(const float* __restrict__ scores_b, int* __restrict__ ghist_b,
                const float* __restrict__ X_b, float* __restrict__ z_b, int N) {
    __shared__ int h[NBINS];
    __shared__ int cs[1024];
    __shared__ int s_bin, s_need;
    __shared__ int cnt_gt, cnt_eq;
    __shared__ int sidx[K];
    __shared__ float sval[K];
    __shared__ unsigned int ek[EQLDS];
    __shared__ int ei[EQLDS];
    __shared__ float ev[EQLDS];
    __shared__ int out_idx[K];
    __shared__ float out_tanh[K];
    int tid = threadIdx.x;
    size_t task = blockIdx.x;
    const float* scores = scores_b + task * N;
    int* ghist = ghist_b + task * NBINS;
    const float* X = X_b + task * (size_t)N * FIN;
    float* z = z_b + task * (size_t)FIN * K;

    // --- stage 1: histogram -> LDS, find critical bin ---
    for (int i = tid; i < NBINS; i += 1024) h[i] = ghist[i];
    if (tid == 0) { cnt_gt = 0; cnt_eq = 0; }
    __syncthreads();
    // self-zero global hist for next user
    for (int i = tid; i < NBINS; i += 1024) ghist[i] = 0;
    int s = 0;
#pragma unroll
    for (int i = 0; i < NBINS / 1024; i++) s += h[tid * (NBINS / 1024) + i];
    cs[tid] = s;
    __syncthreads();
    for (int off = 1; off < 1024; off <<= 1) {
        int v = (tid + off < 1024) ? cs[tid + off] : 0;
        __syncthreads();
        cs[tid] += v;
        __syncthreads();
    }
    {
        int run = (tid == 1023) ? 0 : cs[tid + 1];  // suffix sum beyond this chunk
        const int CH = NBINS / 1024;
        for (int b = tid * CH + CH - 1; b >= tid * CH; b--) {
            int Sb = run + h[b];
            if (Sb >= K && run < K) { s_bin = b; s_need = K - run; }
            run = Sb;
        }
    }
    __syncthreads();
    int bin = s_bin, need = s_need;

    // --- stage 2: collect candidates into LDS ---
    for (int n = tid; n < N; n += 1024) {
        float sc = scores[n];
        unsigned int key = key_of(sc);
        int kb = (int)(key >> BINSHIFT);
        if (kb > bin) {
            int p = atomicAdd(&cnt_gt, 1);
            sidx[p] = n; sval[p] = sc;
        } else if (kb == bin) {
            int p = atomicAdd(&cnt_eq, 1);
            if (p < EQLDS) { ei[p] = n; ek[p] = key; ev[p] = sc; }
        }
    }
    __syncthreads();
    int g = cnt_gt;                       // == K - need
    int m = min(cnt_eq, EQLDS);

    // --- stage 3: exact rank within critical bin (ties -> lower idx) ---
    for (int i = tid; i < m; i += 1024) {
        int myi = ei[i];
        unsigned int myk = ek[i];
        int rank = 0;
        for (int j = 0; j < m; j++)
            rank += (ek[j] > myk) || (ek[j] == myk && ei[j] < myi);
        if (rank < need) { sidx[g + rank] = myi; sval[g + rank] = ev[i]; }
    }
    __syncthreads();

    // --- stage 4: exact sort of the K winners (val desc, idx asc) ---
    if (tid < K) {
        float v = sval[tid];
        int id = sidx[tid];
        unsigned int myk = key_of(v);
        int rank = 0;
        for (int j = 0; j < K; j++) {
            unsigned int kj = key_of(sval[j]);
            rank += (kj > myk) || (kj == myk && sidx[j] < id);
        }
        out_idx[rank] = id;
        out_tanh[rank] = tanhf(v);
    }
    __syncthreads();

    // --- stage 5: z build (coalesced in r) ---
    for (int i = tid; i < K * FIN; i += 1024) {
        int j = i >> 7;        // / FIN
        int r = i & 127;       // % FIN
        z[r * K + j] = X[(size_t)out_idx[j] * FIN + r] * out_tanh[j];
    }
}

// ---------------- fused GRU: upd/rst/hcap/Qn in one kernel ----------------
template <int COLS>
__global__ void __launch_bounds__(256)
gru_fused_kernel(const float* __restrict__ z, const float* __restrict__ Q,
                 const float* __restrict__ Wu, const float* __restrict__ Uu, const float* __restrict__ Bu,
                 const float* __restrict__ Wr, const float* __restrict__ Ur, const float* __restrict__ Br,
                 const float* __restrict__ Wh, const float* __restrict__ Uh, const float* __restrict__ Bh,
                 float* __restrict__ Qn) {
    __shared__ float zc[128][8];
    __shared__ float qc[128][8];
    __shared__ float rq[128][8];
    __shared__ float ul[128][8];
    int tid = threadIdx.x;
    int c0 = blockIdx.x * 8;
    for (int i = tid; i < 1024; i += 256) {
        int r = i >> 3, c = i & 7;
        zc[r][c] = z[r * COLS + c0 + c];
        qc[r][c] = Q[r * COLS + c0 + c];
    }
    __syncthreads();
#pragma unroll
    for (int e = 0; e < 4; e++) {
        int idx = tid + 256 * e;
        int r = idx >> 3, c = idx & 7;
        float au = Bu[r * COLS + c0 + c], ar = Br[r * COLS + c0 + c];
        for (int k = 0; k < 128; k++) {
            float zz = zc[k][c], qq = qc[k][c];
            au += Wu[r * 128 + k] * zz + Uu[r * 128 + k] * qq;
            ar += Wr[r * 128 + k] * zz + Ur[r * 128 + k] * qq;
        }
        ul[r][c] = sigmoidf_(au);
        rq[r][c] = sigmoidf_(ar) * qc[r][c];
    }
    __syncthreads();
#pragma unroll
    for (int e = 0; e < 4; e++) {
        int idx = tid + 256 * e;
        int r = idx >> 3, c = idx & 7;
        float s = Bh[r * COLS + c0 + c];
        for (int k = 0; k < 128; k++) {
            s += Wh[r * 128 + k] * zc[k][c] + Uh[r * 128 + k] * rq[k][c];
        }
        float h = tanhf(s);
        float u = ul[r][c];
        Qn[r * COLS + c0 + c] = (1.f - u) * qc[r][c] + u * h;
    }
}

// ---------------- XW = X @ Qn -> fp32 or bf16 out ----------------
// BF16 only safe when nothing downstream does top-k selection on this path.
template <int COLS, bool BF16>
__global__ void __launch_bounds__(256)
xw_kernel(const float* __restrict__ X, const float* __restrict__ Qn,
          void* __restrict__ outp, int N) {
    constexpr int TPR = COLS / 4;       // threads per row (32 or 16)
    constexpr int RPG = 256 / TPR;      // rows per group (8 or 16)
    constexpr int RPB = RPG * 4;        // rows per block (32 or 64)
    __shared__ float4 qs[128 * TPR];
    for (int i = threadIdx.x; i < 128 * TPR; i += 256) qs[i] = ((const float4*)Qn)[i];
    __syncthreads();
    int lane_c = threadIdx.x % TPR;
    int rloc = threadIdx.x / TPR;
    int base = blockIdx.x * RPB;
    int rows[4];
    float4 acc[4];
#pragma unroll
    for (int j = 0; j < 4; j++) {
        rows[j] = base + rloc + j * RPG;
        acc[j] = make_float4(0.f, 0.f, 0.f, 0.f);
    }
    int nc[4];
#pragma unroll
    for (int j = 0; j < 4; j++) nc[j] = min(rows[j], N - 1);

    for (int k4 = 0; k4 < 32; k4++) {
        float4 q0 = qs[(k4 * 4 + 0) * TPR + lane_c];
        float4 q1 = qs[(k4 * 4 + 1) * TPR + lane_c];
        float4 q2 = qs[(k4 * 4 + 2) * TPR + lane_c];
        float4 q3 = qs[(k4 * 4 + 3) * TPR + lane_c];
#pragma unroll
        for (int j = 0; j < 4; j++) {
            float4 xv = ((const float4*)(X + (size_t)nc[j] * FIN))[k4];
            acc[j].x += xv.x * q0.x + xv.y * q1.x + xv.z * q2.x + xv.w * q3.x;
            acc[j].y += xv.x * q0.y + xv.y * q1.y + xv.z * q2.y + xv.w * q3.y;
            acc[j].z += xv.x * q0.z + xv.y * q1.z + xv.z * q2.z + xv.w * q3.z;
            acc[j].w += xv.x * q0.w + xv.y * q1.w + xv.z * q2.w + xv.w * q3.w;
        }
    }
#pragma unroll
    for (int j = 0; j < 4; j++) {
        if (rows[j] < N) {
            if (BF16) {
                ushort4 o;
                o.x = f2bf(acc[j].x); o.y = f2bf(acc[j].y);
                o.z = f2bf(acc[j].z); o.w = f2bf(acc[j].w);
                ((ushort4*)((unsigned short*)outp + (size_t)rows[j] * COLS))[lane_c] = o;
            } else {
                ((float4*)((float*)outp + (size_t)rows[j] * COLS))[lane_c] = acc[j];
            }
        }
    }
}

// ---------------- batched CSR build over all 4 timesteps ----------------
// grid: (ceil(E/256), T_STEPS)
__global__ void hist4_kernel(const int* __restrict__ dst, int* __restrict__ hist4, int E) {
    int e = blockIdx.x * blockDim.x + threadIdx.x;
    if (e >= E) return;
    int t = blockIdx.y;
    atomicAdd(&hist4[t * NNODES + dst[(size_t)t * E + e]], 1);
}

__global__ void __launch_bounds__(256)
scanA_kernel(const int* __restrict__ hist, int* __restrict__ incl, int* __restrict__ bsum, int M) {
    __shared__ int sh[256];
    int gid = blockIdx.x * 256 + threadIdx.x;
    int v = (gid < M) ? hist[gid] : 0;
    sh[threadIdx.x] = v;
    __syncthreads();
    for (int off = 1; off < 256; off <<= 1) {
        int u = (threadIdx.x >= off) ? sh[threadIdx.x - off] : 0;
        __syncthreads();
        sh[threadIdx.x] += u;
        __syncthreads();
    }
    if (gid < M) incl[gid] = sh[threadIdx.x];
    if (threadIdx.x == 255) bsum[blockIdx.x] = sh[255];
}

__global__ void __launch_bounds__(1024)
scanB_kernel(int* __restrict__ bsum, int nb) {
    __shared__ int sh[1024];
    int tid = threadIdx.x;
    int v = (tid < nb) ? bsum[tid] : 0;
    sh[tid] = v;
    __syncthreads();
    for (int off = 1; off < 1024; off <<= 1) {
        int u = (tid >= off) ? sh[tid - off] : 0;
        __syncthreads();
        sh[tid] += u;
        __syncthreads();
    }
    if (tid < nb) bsum[tid] = (tid == 0) ? 0 : sh[tid - 1];
}

__global__ void __launch_bounds__(256)
scanC_kernel(const int* __restrict__ hist, const int* __restrict__ incl,
             const int* __restrict__ bsum, int* __restrict__ row_ptr,
             int* __restrict__ cursor, int M) {
    int gid = blockIdx.x * 256 + threadIdx.x;
    if (gid < M) {
        int inc = incl[gid] + bsum[gid / 256];
        int ex = inc - hist[gid];
        row_ptr[gid] = ex;
        cursor[gid] = ex;
        if (gid == M - 1) row_ptr[M] = inc;
    }
}

// packed (src, weight-bits) -> ONE 8B random store per edge (halves dirty lines vs two 4B stores)
__global__ void bucket4_kernel(const int* __restrict__ src, const int* __restrict__ dst,
                               const float* __restrict__ w, int* __restrict__ cursor,
                               int2* __restrict__ sedge, int E) {
    int e = blockIdx.x * blockDim.x + threadIdx.x;
    if (e >= E) return;
    int t = blockIdx.y;
    size_t ge = (size_t)t * E + e;
    int d = dst[ge];
    int pos = atomicAdd(&cursor[t * NNODES + d], 1);
    int2 pk;
    pk.x = src[ge];
    pk.y = __float_as_int(w[ge]);
    sedge[pos] = pk;
}

// ---------------- CSR aggregation: out[d] = relu(sum w_e * XW[src_e]) ----------------
// SCORE: also compute next-layer scores = out_row @ scorer / nrm + mask, and topk histogram
template <int COLS, bool SCORE, bool BF16>
__global__ void __launch_bounds__(256)
agg_kernel(const void* __restrict__ XWp, const int* __restrict__ row_ptr,
           const int2* __restrict__ sedge,
           float* __restrict__ out, int N,
           const float* __restrict__ scorer, const float* __restrict__ norms,
           const float* __restrict__ mask, float* __restrict__ scores, int* __restrict__ ghist) {
    constexpr int TPN = COLS / 4;       // threads per node (32 or 16)
    constexpr int NPB = 256 / TPN;      // nodes per block (8 or 16)
    int node = blockIdx.x * NPB + threadIdx.x / TPN;
    int lane = threadIdx.x % TPN;
    if (node >= N) return;
    int beg = row_ptr[node], end = row_ptr[node + 1];
    float4 acc = make_float4(0.f, 0.f, 0.f, 0.f);
    for (int i = beg; i < end; i++) {
        int2 pk = sedge[i];
        int s = pk.x;
        float wt = __int_as_float(pk.y);
        if (BF16) {
            ushort4 v = ((const ushort4*)((const unsigned short*)XWp + (size_t)s * COLS))[lane];
            acc.x += bf2f(v.x) * wt; acc.y += bf2f(v.y) * wt;
            acc.z += bf2f(v.z) * wt; acc.w += bf2f(v.w) * wt;
        } else {
            float4 v = ((const float4*)((const float*)XWp + (size_t)s * COLS))[lane];
            acc.x += v.x * wt; acc.y += v.y * wt; acc.z += v.z * wt; acc.w += v.w * wt;
        }
    }
    acc.x = fmaxf(acc.x, 0.f); acc.y = fmaxf(acc.y, 0.f);
    acc.z = fmaxf(acc.z, 0.f); acc.w = fmaxf(acc.w, 0.f);
    ((float4*)(out + (size_t)node * COLS))[lane] = acc;
    if (SCORE) {
        float4 sc4 = ((const float4*)scorer)[lane];
        float partial = acc.x * sc4.x + acc.y * sc4.y + acc.z * sc4.z + acc.w * sc4.w;
#pragma unroll
        for (int off = TPN / 2; off > 0; off >>= 1) partial += __shfl_xor(partial, off, TPN);
        if (lane == 0) {
            float s = partial / norms[1] + mask[node];
            scores[node] = s;
            atomicAdd(&ghist[key_of(s) >> BINSHIFT], 1);
        }
    }
}

extern "C" void kernel_launch(void* const* d_in, const int* in_sizes, int n_in,
                              void* d_out, int out_size, void* d_ws, size_t ws_size,
                              hipStream_t stream) {
    const float* node_embs   = (const float*)d_in[0];
    const float* mask        = (const float*)d_in[1];
    const int*   edge_src    = (const int*)d_in[2];
    const int*   edge_dst    = (const int*)d_in[3];
    const float* edge_weight = (const float*)d_in[4];
    const float* gcn_w0      = (const float*)d_in[5];
    const float* gcn_w1      = (const float*)d_in[6];
    const float* l0p[10];
    const float* l1p[10];
    for (int i = 0; i < 10; i++) l0p[i] = (const float*)d_in[7 + i];
    for (int i = 0; i < 10; i++) l1p[i] = (const float*)d_in[17 + i];
    // l*p: 0=Wu 1=Uu 2=Bu 3=Wr 4=Ur 5=Br 6=Wh 7=Uh 8=Bh 9=scorer

    char* ws = (char*)d_ws;
    size_t off = 0;
    auto alloc = [&](size_t bytes) -> void* {
        void* p = ws + off;
        off += (bytes + 255) / 256 * 256;
        return p;
    };
    float* XWbuf  = (float*)alloc((size_t)NNODES * 128 * 4);   // fp32 L0 / bf16 L1 (reuse)
    float* h1buf  = (float*)alloc((size_t)NNODES * 128 * 4);
    float* scores4= (float*)alloc((size_t)4 * NNODES * 4);     // L0 scores for all t
    float* scores1= (float*)alloc((size_t)NNODES * 4);         // L1 scores (per t)
    float* z0buf  = (float*)alloc((size_t)4 * 128 * 128 * 4);  // L0 z for all t
    float* z1buf  = (float*)alloc(128 * 64 * 4);
    float* Q0a    = (float*)alloc(128 * 128 * 4);
    float* Q0b    = (float*)alloc(128 * 128 * 4);
    float* Q1a    = (float*)alloc(128 * 64 * 4);
    float* Q1b    = (float*)alloc(128 * 64 * 4);
    float* norms  = (float*)alloc(64);
    // combined zeroed region: hist4[4N] + ghist0[4*NBINS] + ghist1[NBINS]
    int* hist4    = (int*)alloc(((size_t)4 * NNODES + 5 * NBINS) * 4);
    int* ghist0   = hist4 + 4 * NNODES;
    int* ghist1   = ghist0 + 4 * NBINS;
    int* incl4    = (int*)alloc((size_t)4 * NNODES * 4);
    int* bsumb    = (int*)alloc(1024 * 4);
    int* rowp4    = (int*)alloc(((size_t)4 * NNODES + 1) * 4);
    int* cursor4  = (int*)alloc((size_t)4 * NNODES * 4);
    int2* sedge4  = (int2*)alloc((size_t)4 * NEDGES * 8);

    hipMemcpyAsync(Q0a, gcn_w0, 128 * 128 * 4, hipMemcpyDeviceToDevice, stream);
    hipMemcpyAsync(Q1a, gcn_w1, 128 * 64 * 4, hipMemcpyDeviceToDevice, stream);
    hipMemsetAsync(hist4, 0, ((size_t)4 * NNODES + 5 * NBINS) * 4, stream);
    norm_kernel<<<1, 128, 0, stream>>>(l0p[9], l1p[9], norms);

    const int M4 = 4 * NNODES;
    const int NB4 = (M4 + 255) / 256;          // 782
    const int NB = (NNODES + 255) / 256;       // 196
    const int EB = (NEDGES + 255) / 256;       // 1563

    // ---- batched CSR build for all 4 timesteps ----
    hist4_kernel<<<dim3(EB, 4), 256, 0, stream>>>(edge_dst, hist4, NEDGES);
    scanA_kernel<<<NB4, 256, 0, stream>>>(hist4, incl4, bsumb, M4);
    scanB_kernel<<<1, 1024, 0, stream>>>(bsumb, NB4);
    scanC_kernel<<<NB4, 256, 0, stream>>>(hist4, incl4, bsumb, rowp4, cursor4, M4);
    bucket4_kernel<<<dim3(EB, 4), 256, 0, stream>>>(edge_src, edge_dst, edge_weight, cursor4, sedge4, NEDGES);

    // ---- L0 scores + top-k + z for ALL t (input-only dependence) ----
    scores_hist4_kernel<<<dim3(NB, 4), 256, 0, stream>>>(node_embs, l0p[9], norms, mask, scores4, ghist0, NNODES);
    topk_all_kernel<128><<<4, 1024, 0, stream>>>(scores4, ghist0, node_embs, z0buf, NNODES);

    float* Q0cur = Q0a; float* Q0nxt = Q0b;
    float* Q1cur = Q1a; float* Q1nxt = Q1b;

    for (int t = 0; t < T_STEPS; t++) {
        const float* X0 = node_embs + (size_t)t * NNODES * 128;
        const float* mk = mask + (size_t)t * NNODES;
        const int* rp_t = rowp4 + (size_t)t * NNODES;

        // ---- layer 0 (fp32 XW: h1 feeds layer-1 top-k selection, must stay exact) ----
        gru_fused_kernel<128><<<16, 256, 0, stream>>>(z0buf + (size_t)t * 128 * 128, Q0cur,
            l0p[0], l0p[1], l0p[2], l0p[3], l0p[4], l0p[5], l0p[6], l0p[7], l0p[8], Q0nxt);
        xw_kernel<128, false><<<(NNODES + 31) / 32, 256, 0, stream>>>(X0, Q0nxt, XWbuf, NNODES);
        agg_kernel<128, true, false><<<(NNODES + 7) / 8, 256, 0, stream>>>(XWbuf, rp_t, sedge4, h1buf, NNODES,
            l1p[9], norms, mk, scores1, ghist1);

        // ---- layer 1 (h1buf relu'd; scores1/ghist1 built by agg above; bf16 XW: output-only path) ----
        topk_all_kernel<64><<<1, 1024, 0, stream>>>(scores1, ghist1, h1buf, z1buf, NNODES);
        gru_fused_kernel<64><<<8, 256, 0, stream>>>(z1buf, Q1cur,
            l1p[0], l1p[1], l1p[2], l1p[3], l1p[4], l1p[5], l1p[6], l1p[7], l1p[8], Q1nxt);
        xw_kernel<64, true><<<(NNODES + 63) / 64, 256, 0, stream>>>(h1buf, Q1nxt, XWbuf, NNODES);
        float* out_t = (float*)d_out + (size_t)t * NNODES * 64;
        agg_kernel<64, false, true><<<(NNODES + 15) / 16, 256, 0, stream>>>(XWbuf, rp_t, sedge4, out_t, NNODES,
            nullptr, nullptr, nullptr, nullptr, nullptr);

        float* tmp;
        tmp = Q0cur; Q0cur = Q0nxt; Q0nxt = tmp;
        tmp = Q1cur; Q1cur = Q1nxt; Q1nxt = tmp;
    }
}

// Round 7
// 1618.112 us; speedup vs baseline: 1.1406x; 1.0537x over previous
//
#include <hip/hip_runtime.h>
#include <math.h>

#define T_STEPS 4
#define NNODES 50000
#define NEDGES 400000
#define FIN 128   // input feature dim for both layers
#define NBINS 8192
#define BINSHIFT 19  // 32-13
#define EQCAP 4096
#define DSHARD 6250  // NNODES/8

__device__ __forceinline__ float sigmoidf_(float x) { return 1.0f / (1.0f + __expf(-x)); }

__device__ __forceinline__ unsigned int key_of(float s) {
    unsigned int u = __float_as_uint(s);
    return (u & 0x80000000u) ? ~u : (u | 0x80000000u);
}

__device__ __forceinline__ unsigned short f2bf(float f) {
    unsigned int u = __float_as_uint(f);
    unsigned int r = (u + 0x7FFFu + ((u >> 16) & 1u)) >> 16;
    return (unsigned short)r;
}
__device__ __forceinline__ float bf2f(unsigned short h) {
    return __uint_as_float(((unsigned int)h) << 16);
}

// ---------------- norms of the two scorers ----------------
__global__ void norm_kernel(const float* __restrict__ s0, const float* __restrict__ s1,
                            float* __restrict__ norms) {
    __shared__ float red[128];
    int tid = threadIdx.x;  // 128 threads
    float a = s0[tid];
    red[tid] = a * a;
    __syncthreads();
    for (int off = 64; off > 0; off >>= 1) { if (tid < off) red[tid] += red[tid + off]; __syncthreads(); }
    if (tid == 0) norms[0] = sqrtf(red[0]);
    __syncthreads();
    float b = s1[tid];
    red[tid] = b * b;
    __syncthreads();
    for (int off = 64; off > 0; off >>= 1) { if (tid < off) red[tid] += red[tid + off]; __syncthreads(); }
    if (tid == 0) norms[1] = sqrtf(red[0]);
}

// ---------------- L0 scores for ALL t + topk histogram ----------------
// grid: (ceil(N/256), T_STEPS)
__global__ void scores_hist4_kernel(const float* __restrict__ node_embs, const float* __restrict__ scorer,
                                    const float* __restrict__ norms,
                                    const float* __restrict__ mask, float* __restrict__ scores4,
                                    int* __restrict__ ghist4, int N) {
    __shared__ float sc[FIN];
    if (threadIdx.x < FIN) sc[threadIdx.x] = scorer[threadIdx.x];
    __syncthreads();
    int t = blockIdx.y;
    int n = blockIdx.x * blockDim.x + threadIdx.x;
    if (n >= N) return;
    const float4* xr = (const float4*)(node_embs + ((size_t)t * N + n) * FIN);
    float acc = 0.f;
#pragma unroll 8
    for (int k4 = 0; k4 < FIN / 4; k4++) {
        float4 v = xr[k4];
        acc += v.x * sc[k4 * 4] + v.y * sc[k4 * 4 + 1] + v.z * sc[k4 * 4 + 2] + v.w * sc[k4 * 4 + 3];
    }
    float s = acc / norms[0] + mask[(size_t)t * N + n];
    scores4[(size_t)t * N + n] = s;
    atomicAdd(&ghist4[t * NBINS + (key_of(s) >> BINSHIFT)], 1);
}

// ---------------- parallel top-k collect: each block re-derives critical bin ----------------
// grid: (196, ntasks). task strides: scores N, ghist NBINS, cnts 2, gt 128, eq EQCAP
__global__ void __launch_bounds__(256)
topk_collect_kernel(const float* __restrict__ scores_b, const int* __restrict__ ghist_b,
                    int* __restrict__ cnts_b, int* __restrict__ gt_idx_b, float* __restrict__ gt_val_b,
                    int* __restrict__ eq_idx_b, float* __restrict__ eq_val_b, int N, int K) {
    __shared__ int h[NBINS];
    __shared__ int part[256];
    __shared__ int s_bin;
    int tid = threadIdx.x;
    int task = blockIdx.y;
    const int* gh = ghist_b + (size_t)task * NBINS;
    for (int i = tid; i < NBINS; i += 256) h[i] = gh[i];
    __syncthreads();
    int s = 0;
#pragma unroll
    for (int i = 0; i < NBINS / 256; i++) s += h[tid * (NBINS / 256) + i];
    part[tid] = s;
    __syncthreads();
    for (int off = 1; off < 256; off <<= 1) {
        int v = (tid + off < 256) ? part[tid + off] : 0;
        __syncthreads();
        part[tid] += v;
        __syncthreads();
    }
    {
        int run = (tid == 255) ? 0 : part[tid + 1];
        const int CH = NBINS / 256;
        for (int b = tid * CH + CH - 1; b >= tid * CH; b--) {
            int Sb = run + h[b];
            if (Sb >= K && run < K) s_bin = b;
            run = Sb;
        }
    }
    __syncthreads();
    int bin = s_bin;
    const float* scores = scores_b + (size_t)task * N;
    int* cg = cnts_b + task * 2;
    for (int n = blockIdx.x * 256 + tid; n < N; n += gridDim.x * 256) {
        float sc = scores[n];
        unsigned int key = key_of(sc);
        int kb = (int)(key >> BINSHIFT);
        if (kb > bin) {
            int p = atomicAdd(&cg[0], 1);
            gt_idx_b[task * 128 + p] = n; gt_val_b[task * 128 + p] = sc;
        } else if (kb == bin) {
            int p = atomicAdd(&cg[1], 1);
            if (p < EQCAP) { eq_idx_b[task * EQCAP + p] = n; eq_val_b[task * EQCAP + p] = sc; }
        }
    }
}

// ---------------- finish: exact rank + sort + z build; self-zero ghist & cnts ----------------
// grid: (ntasks). need = K - cnt_gt. z[r*K+j] = X[idx_j*FIN+r]*tanh(val_j)
template <int K>
__global__ void __launch_bounds__(1024)
topk_finish_kernel(int* __restrict__ ghist_b, int* __restrict__ cnts_b,
                   const int* __restrict__ gt_idx_b, const float* __restrict__ gt_val_b,
                   const int* __restrict__ eq_idx_b, const float* __restrict__ eq_val_b,
                   const float* __restrict__ X_b, float* __restrict__ z_b, int N) {
    __shared__ int sidx[K];
    __shared__ float sval[K];
    __shared__ unsigned int ek[EQCAP];
    __shared__ int ei[EQCAP];
    __shared__ int out_idx[K];
    __shared__ float out_tanh[K];
    int tid = threadIdx.x;
    int task = blockIdx.x;
    int* cg = cnts_b + task * 2;
    int g = cg[0];
    int m = min(cg[1], EQCAP);
    int need = K - g;
    const int* gt_idx = gt_idx_b + task * 128;
    const float* gt_val = gt_val_b + task * 128;
    const int* eq_idx = eq_idx_b + task * EQCAP;
    const float* eq_val = eq_val_b + task * EQCAP;
    const float* X = X_b + (size_t)task * N * FIN;
    float* z = z_b + (size_t)task * FIN * K;

    for (int i = tid; i < g; i += 1024) { sidx[i] = gt_idx[i]; sval[i] = gt_val[i]; }
    for (int i = tid; i < m; i += 1024) { ek[i] = key_of(eq_val[i]); ei[i] = eq_idx[i]; }
    __syncthreads();
    for (int i = tid; i < m; i += 1024) {
        int myi = ei[i];
        unsigned int myk = ek[i];
        int rank = 0;
        for (int j = 0; j < m; j++)
            rank += (ek[j] > myk) || (ek[j] == myk && ei[j] < myi);
        if (rank < need) { sidx[g + rank] = myi; sval[g + rank] = eq_val[i]; }
    }
    __syncthreads();
    if (tid < K) {
        float v = sval[tid];
        int id = sidx[tid];
        unsigned int myk = key_of(v);
        int rank = 0;
        for (int j = 0; j < K; j++) {
            unsigned int kj = key_of(sval[j]);
            rank += (kj > myk) || (kj == myk && sidx[j] < id);
        }
        out_idx[rank] = id;
        out_tanh[rank] = tanhf(v);
    }
    // self-zero for next reuse
    int* gh = ghist_b + (size_t)task * NBINS;
    for (int i = tid; i < NBINS; i += 1024) gh[i] = 0;
    if (tid == 0) { cg[0] = 0; cg[1] = 0; }
    __syncthreads();
    for (int i = tid; i < K * FIN; i += 1024) {
        int j = i >> 7;        // / FIN
        int r = i & 127;       // % FIN
        z[r * K + j] = X[(size_t)out_idx[j] * FIN + r] * out_tanh[j];
    }
}

// ---------------- fused GRU: upd/rst/hcap/Qn in one kernel ----------------
template <int COLS>
__global__ void __launch_bounds__(256)
gru_fused_kernel(const float* __restrict__ z, const float* __restrict__ Q,
                 const float* __restrict__ Wu, const float* __restrict__ Uu, const float* __restrict__ Bu,
                 const float* __restrict__ Wr, const float* __restrict__ Ur, const float* __restrict__ Br,
                 const float* __restrict__ Wh, const float* __restrict__ Uh, const float* __restrict__ Bh,
                 float* __restrict__ Qn) {
    __shared__ float zc[128][8];
    __shared__ float qc[128][8];
    __shared__ float rq[128][8];
    __shared__ float ul[128][8];
    int tid = threadIdx.x;
    int c0 = blockIdx.x * 8;
    for (int i = tid; i < 1024; i += 256) {
        int r = i >> 3, c = i & 7;
        zc[r][c] = z[r * COLS + c0 + c];
        qc[r][c] = Q[r * COLS + c0 + c];
    }
    __syncthreads();
#pragma unroll
    for (int e = 0; e < 4; e++) {
        int idx = tid + 256 * e;
        int r = idx >> 3, c = idx & 7;
        float au = Bu[r * COLS + c0 + c], ar = Br[r * COLS + c0 + c];
        for (int k = 0; k < 128; k++) {
            float zz = zc[k][c], qq = qc[k][c];
            au += Wu[r * 128 + k] * zz + Uu[r * 128 + k] * qq;
            ar += Wr[r * 128 + k] * zz + Ur[r * 128 + k] * qq;
        }
        ul[r][c] = sigmoidf_(au);
        rq[r][c] = sigmoidf_(ar) * qc[r][c];
    }
    __syncthreads();
#pragma unroll
    for (int e = 0; e < 4; e++) {
        int idx = tid + 256 * e;
        int r = idx >> 3, c = idx & 7;
        float s = Bh[r * COLS + c0 + c];
        for (int k = 0; k < 128; k++) {
            s += Wh[r * 128 + k] * zc[k][c] + Uh[r * 128 + k] * rq[k][c];
        }
        float h = tanhf(s);
        float u = ul[r][c];
        Qn[r * COLS + c0 + c] = (1.f - u) * qc[r][c] + u * h;
    }
}

// ---------------- XW = X @ Qn -> fp32 or bf16 out ----------------
template <int COLS, bool BF16>
__global__ void __launch_bounds__(256)
xw_kernel(const float* __restrict__ X, const float* __restrict__ Qn,
          void* __restrict__ outp, int N) {
    constexpr int TPR = COLS / 4;
    constexpr int RPG = 256 / TPR;
    constexpr int RPB = RPG * 4;
    __shared__ float4 qs[128 * TPR];
    for (int i = threadIdx.x; i < 128 * TPR; i += 256) qs[i] = ((const float4*)Qn)[i];
    __syncthreads();
    int lane_c = threadIdx.x % TPR;
    int rloc = threadIdx.x / TPR;
    int base = blockIdx.x * RPB;
    int rows[4];
    float4 acc[4];
#pragma unroll
    for (int j = 0; j < 4; j++) {
        rows[j] = base + rloc + j * RPG;
        acc[j] = make_float4(0.f, 0.f, 0.f, 0.f);
    }
    int nc[4];
#pragma unroll
    for (int j = 0; j < 4; j++) nc[j] = min(rows[j], N - 1);

    for (int k4 = 0; k4 < 32; k4++) {
        float4 q0 = qs[(k4 * 4 + 0) * TPR + lane_c];
        float4 q1 = qs[(k4 * 4 + 1) * TPR + lane_c];
        float4 q2 = qs[(k4 * 4 + 2) * TPR + lane_c];
        float4 q3 = qs[(k4 * 4 + 3) * TPR + lane_c];
#pragma unroll
        for (int j = 0; j < 4; j++) {
            float4 xv = ((const float4*)(X + (size_t)nc[j] * FIN))[k4];
            acc[j].x += xv.x * q0.x + xv.y * q1.x + xv.z * q2.x + xv.w * q3.x;
            acc[j].y += xv.x * q0.y + xv.y * q1.y + xv.z * q2.y + xv.w * q3.y;
            acc[j].z += xv.x * q0.z + xv.y * q1.z + xv.z * q2.z + xv.w * q3.z;
            acc[j].w += xv.x * q0.w + xv.y * q1.w + xv.z * q2.w + xv.w * q3.w;
        }
    }
#pragma unroll
    for (int j = 0; j < 4; j++) {
        if (rows[j] < N) {
            if (BF16) {
                ushort4 o;
                o.x = f2bf(acc[j].x); o.y = f2bf(acc[j].y);
                o.z = f2bf(acc[j].z); o.w = f2bf(acc[j].w);
                ((ushort4*)((unsigned short*)outp + (size_t)rows[j] * COLS))[lane_c] = o;
            } else {
                ((float4*)((float*)outp + (size_t)rows[j] * COLS))[lane_c] = acc[j];
            }
        }
    }
}

// ---------------- batched CSR build over all 4 timesteps ----------------
__global__ void hist4_kernel(const int* __restrict__ dst, int* __restrict__ hist4, int E) {
    int e = blockIdx.x * blockDim.x + threadIdx.x;
    if (e >= E) return;
    int t = blockIdx.y;
    atomicAdd(&hist4[t * NNODES + dst[(size_t)t * E + e]], 1);
}

__global__ void __launch_bounds__(256)
scanA_kernel(const int* __restrict__ hist, int* __restrict__ incl, int* __restrict__ bsum, int M) {
    __shared__ int sh[256];
    int gid = blockIdx.x * 256 + threadIdx.x;
    int v = (gid < M) ? hist[gid] : 0;
    sh[threadIdx.x] = v;
    __syncthreads();
    for (int off = 1; off < 256; off <<= 1) {
        int u = (threadIdx.x >= off) ? sh[threadIdx.x - off] : 0;
        __syncthreads();
        sh[threadIdx.x] += u;
        __syncthreads();
    }
    if (gid < M) incl[gid] = sh[threadIdx.x];
    if (threadIdx.x == 255) bsum[blockIdx.x] = sh[255];
}

__global__ void __launch_bounds__(1024)
scanB_kernel(int* __restrict__ bsum, int nb) {
    __shared__ int sh[1024];
    int tid = threadIdx.x;
    int v = (tid < nb) ? bsum[tid] : 0;
    sh[tid] = v;
    __syncthreads();
    for (int off = 1; off < 1024; off <<= 1) {
        int u = (tid >= off) ? sh[tid - off] : 0;
        __syncthreads();
        sh[tid] += u;
        __syncthreads();
    }
    if (tid < nb) bsum[tid] = (tid == 0) ? 0 : sh[tid - 1];
}

__global__ void __launch_bounds__(256)
scanC_kernel(const int* __restrict__ hist, const int* __restrict__ incl,
             const int* __restrict__ bsum, int* __restrict__ row_ptr,
             int* __restrict__ cursor, int M) {
    int gid = blockIdx.x * 256 + threadIdx.x;
    if (gid < M) {
        int inc = incl[gid] + bsum[gid / 256];
        int ex = inc - hist[gid];
        row_ptr[gid] = ex;
        cursor[gid] = ex;
        if (gid == M - 1) row_ptr[M] = inc;
    }
}

// dst-range-sharded scatter: blockIdx.x&7 selects dst shard; CSR positions for a
// dst shard are CONTIGUOUS -> each sedge region written by one block-class
// (XCD-local under the %8 heuristic) so L2 lines coalesce before write-back.
__global__ void bucket4_kernel(const int* __restrict__ src, const int* __restrict__ dst,
                               const float* __restrict__ w, int* __restrict__ cursor,
                               int2* __restrict__ sedge, int E) {
    int bx = blockIdx.x;
    int shard = bx & 7;
    int e = (bx >> 3) * 256 + threadIdx.x;
    if (e >= E) return;
    int t = blockIdx.y;
    size_t ge = (size_t)t * E + e;
    int d = dst[ge];
    if (d / DSHARD != shard) return;
    int pos = atomicAdd(&cursor[t * NNODES + d], 1);
    int2 pk;
    pk.x = src[ge];
    pk.y = __float_as_int(w[ge]);
    sedge[pos] = pk;
}

// ---------------- CSR aggregation: out[d] = relu(sum w_e * XW[src_e]) ----------------
template <int COLS, bool SCORE, bool BF16>
__global__ void __launch_bounds__(256)
agg_kernel(const void* __restrict__ XWp, const int* __restrict__ row_ptr,
           const int2* __restrict__ sedge,
           float* __restrict__ out, int N,
           const float* __restrict__ scorer, const float* __restrict__ norms,
           const float* __restrict__ mask, float* __restrict__ scores, int* __restrict__ ghist) {
    constexpr int TPN = COLS / 4;
    constexpr int NPB = 256 / TPN;
    int node = blockIdx.x * NPB + threadIdx.x / TPN;
    int lane = threadIdx.x % TPN;
    if (node >= N) return;
    int beg = row_ptr[node], end = row_ptr[node + 1];
    float4 acc = make_float4(0.f, 0.f, 0.f, 0.f);
    for (int i = beg; i < end; i++) {
        int2 pk = sedge[i];
        int s = pk.x;
        float wt = __int_as_float(pk.y);
        if (BF16) {
            ushort4 v = ((const ushort4*)((const unsigned short*)XWp + (size_t)s * COLS))[lane];
            acc.x += bf2f(v.x) * wt; acc.y += bf2f(v.y) * wt;
            acc.z += bf2f(v.z) * wt; acc.w += bf2f(v.w) * wt;
        } else {
            float4 v = ((const float4*)((const float*)XWp + (size_t)s * COLS))[lane];
            acc.x += v.x * wt; acc.y += v.y * wt; acc.z += v.z * wt; acc.w += v.w * wt;
        }
    }
    acc.x = fmaxf(acc.x, 0.f); acc.y = fmaxf(acc.y, 0.f);
    acc.z = fmaxf(acc.z, 0.f); acc.w = fmaxf(acc.w, 0.f);
    ((float4*)(out + (size_t)node * COLS))[lane] = acc;
    if (SCORE) {
        float4 sc4 = ((const float4*)scorer)[lane];
        float partial = acc.x * sc4.x + acc.y * sc4.y + acc.z * sc4.z + acc.w * sc4.w;
#pragma unroll
        for (int off = TPN / 2; off > 0; off >>= 1) partial += __shfl_xor(partial, off, TPN);
        if (lane == 0) {
            float s = partial / norms[1] + mask[node];
            scores[node] = s;
            atomicAdd(&ghist[key_of(s) >> BINSHIFT], 1);
        }
    }
}

extern "C" void kernel_launch(void* const* d_in, const int* in_sizes, int n_in,
                              void* d_out, int out_size, void* d_ws, size_t ws_size,
                              hipStream_t stream) {
    const float* node_embs   = (const float*)d_in[0];
    const float* mask        = (const float*)d_in[1];
    const int*   edge_src    = (const int*)d_in[2];
    const int*   edge_dst    = (const int*)d_in[3];
    const float* edge_weight = (const float*)d_in[4];
    const float* gcn_w0      = (const float*)d_in[5];
    const float* gcn_w1      = (const float*)d_in[6];
    const float* l0p[10];
    const float* l1p[10];
    for (int i = 0; i < 10; i++) l0p[i] = (const float*)d_in[7 + i];
    for (int i = 0; i < 10; i++) l1p[i] = (const float*)d_in[17 + i];
    // l*p: 0=Wu 1=Uu 2=Bu 3=Wr 4=Ur 5=Br 6=Wh 7=Uh 8=Bh 9=scorer

    char* ws = (char*)d_ws;
    size_t off = 0;
    auto alloc = [&](size_t bytes) -> void* {
        void* p = ws + off;
        off += (bytes + 255) / 256 * 256;
        return p;
    };
    float* XWbuf  = (float*)alloc((size_t)NNODES * 128 * 4);   // fp32 L0 / bf16 L1 (reuse)
    float* h1buf  = (float*)alloc((size_t)NNODES * 128 * 4);
    float* scores4= (float*)alloc((size_t)4 * NNODES * 4);     // L0 scores (all t)
    float* scores1= (float*)alloc((size_t)NNODES * 4);         // L1 scores (per t)
    float* z0buf  = (float*)alloc((size_t)4 * 128 * 128 * 4);  // L0 z (all t)
    float* z1buf  = (float*)alloc(128 * 64 * 4);
    float* Q0a    = (float*)alloc(128 * 128 * 4);
    float* Q0b    = (float*)alloc(128 * 128 * 4);
    float* Q1a    = (float*)alloc(128 * 64 * 4);
    float* Q1b    = (float*)alloc(128 * 64 * 4);
    float* norms  = (float*)alloc(64);
    // combined zeroed region: hist4[4N] + ghist0[4*NBINS] + ghist1[NBINS] + cnts[64]
    int* hist4    = (int*)alloc(((size_t)4 * NNODES + 5 * NBINS + 64) * 4);
    int* ghist0   = hist4 + 4 * NNODES;
    int* ghist1   = ghist0 + 4 * NBINS;
    int* cnts     = ghist1 + NBINS;      // 4 tasks x 2 (L1 reuses slots 0,1)
    int* incl4    = (int*)alloc((size_t)4 * NNODES * 4);
    int* bsumb    = (int*)alloc(1024 * 4);
    int* rowp4    = (int*)alloc(((size_t)4 * NNODES + 1) * 4);
    int* cursor4  = (int*)alloc((size_t)4 * NNODES * 4);
    int2* sedge4  = (int2*)alloc((size_t)4 * NEDGES * 8);
    int*   gt_idx = (int*)alloc((size_t)4 * 128 * 4);
    float* gt_val = (float*)alloc((size_t)4 * 128 * 4);
    int*   eq_idx = (int*)alloc((size_t)4 * EQCAP * 4);
    float* eq_val = (float*)alloc((size_t)4 * EQCAP * 4);

    hipMemcpyAsync(Q0a, gcn_w0, 128 * 128 * 4, hipMemcpyDeviceToDevice, stream);
    hipMemcpyAsync(Q1a, gcn_w1, 128 * 64 * 4, hipMemcpyDeviceToDevice, stream);
    hipMemsetAsync(hist4, 0, ((size_t)4 * NNODES + 5 * NBINS + 64) * 4, stream);
    norm_kernel<<<1, 128, 0, stream>>>(l0p[9], l1p[9], norms);

    const int M4 = 4 * NNODES;
    const int NB4 = (M4 + 255) / 256;          // 782
    const int NB = (NNODES + 255) / 256;       // 196
    const int EB = (NEDGES + 255) / 256;       // 1563

    // ---- batched CSR build for all 4 timesteps ----
    hist4_kernel<<<dim3(EB, 4), 256, 0, stream>>>(edge_dst, hist4, NEDGES);
    scanA_kernel<<<NB4, 256, 0, stream>>>(hist4, incl4, bsumb, M4);
    scanB_kernel<<<1, 1024, 0, stream>>>(bsumb, NB4);
    scanC_kernel<<<NB4, 256, 0, stream>>>(hist4, incl4, bsumb, rowp4, cursor4, M4);
    bucket4_kernel<<<dim3(EB * 8, 4), 256, 0, stream>>>(edge_src, edge_dst, edge_weight, cursor4, sedge4, NEDGES);

    // ---- L0 scores + top-k + z for ALL t (input-only dependence) ----
    scores_hist4_kernel<<<dim3(NB, 4), 256, 0, stream>>>(node_embs, l0p[9], norms, mask, scores4, ghist0, NNODES);
    topk_collect_kernel<<<dim3(NB, 4), 256, 0, stream>>>(scores4, ghist0, cnts, gt_idx, gt_val, eq_idx, eq_val, NNODES, 128);
    topk_finish_kernel<128><<<4, 1024, 0, stream>>>(ghist0, cnts, gt_idx, gt_val, eq_idx, eq_val, node_embs, z0buf, NNODES);

    float* Q0cur = Q0a; float* Q0nxt = Q0b;
    float* Q1cur = Q1a; float* Q1nxt = Q1b;

    for (int t = 0; t < T_STEPS; t++) {
        const float* X0 = node_embs + (size_t)t * NNODES * 128;
        const float* mk = mask + (size_t)t * NNODES;
        const int* rp_t = rowp4 + (size_t)t * NNODES;

        // ---- layer 0 (fp32 XW: h1 feeds layer-1 top-k selection, must stay exact) ----
        gru_fused_kernel<128><<<16, 256, 0, stream>>>(z0buf + (size_t)t * 128 * 128, Q0cur,
            l0p[0], l0p[1], l0p[2], l0p[3], l0p[4], l0p[5], l0p[6], l0p[7], l0p[8], Q0nxt);
        xw_kernel<128, false><<<(NNODES + 31) / 32, 256, 0, stream>>>(X0, Q0nxt, XWbuf, NNODES);
        agg_kernel<128, true, false><<<(NNODES + 7) / 8, 256, 0, stream>>>(XWbuf, rp_t, sedge4, h1buf, NNODES,
            l1p[9], norms, mk, scores1, ghist1);

        // ---- layer 1 (h1buf relu'd; scores1/ghist1 from agg; bf16 XW: output-only path) ----
        topk_collect_kernel<<<dim3(NB, 1), 256, 0, stream>>>(scores1, ghist1, cnts, gt_idx, gt_val, eq_idx, eq_val, NNODES, 64);
        topk_finish_kernel<64><<<1, 1024, 0, stream>>>(ghist1, cnts, gt_idx, gt_val, eq_idx, eq_val, h1buf, z1buf, NNODES);
        gru_fused_kernel<64><<<8, 256, 0, stream>>>(z1buf, Q1cur,
            l1p[0], l1p[1], l1p[2], l1p[3], l1p[4], l1p[5], l1p[6], l1p[7], l1p[8], Q1nxt);
        xw_kernel<64, true><<<(NNODES + 63) / 64, 256, 0, stream>>>(h1buf, Q1nxt, XWbuf, NNODES);
        float* out_t = (float*)d_out + (size_t)t * NNODES * 64;
        agg_kernel<64, false, true><<<(NNODES + 15) / 16, 256, 0, stream>>>(XWbuf, rp_t, sedge4, out_t, NNODES,
            nullptr, nullptr, nullptr, nullptr, nullptr);

        float* tmp;
        tmp = Q0cur; Q0cur = Q0nxt; Q0nxt = tmp;
        tmp = Q1cur; Q1cur = Q1nxt; Q1nxt = tmp;
    }
}

// Round 8
// 1597.826 us; speedup vs baseline: 1.1551x; 1.0127x over previous
//
#include <hip/hip_runtime.h>
#include <math.h>

#define T_STEPS 4
#define NNODES 50000
#define NEDGES 400000
#define FIN 128   // input feature dim for both layers
#define NBINS 8192
#define BINSHIFT 19  // 32-13
#define EQCAP 4096
#define DSHARD 6250  // NNODES/8

__device__ __forceinline__ float sigmoidf_(float x) { return 1.0f / (1.0f + __expf(-x)); }

__device__ __forceinline__ unsigned int key_of(float s) {
    unsigned int u = __float_as_uint(s);
    return (u & 0x80000000u) ? ~u : (u | 0x80000000u);
}

__device__ __forceinline__ unsigned short f2bf(float f) {
    unsigned int u = __float_as_uint(f);
    unsigned int r = (u + 0x7FFFu + ((u >> 16) & 1u)) >> 16;
    return (unsigned short)r;
}
__device__ __forceinline__ float bf2f(unsigned short h) {
    return __uint_as_float(((unsigned int)h) << 16);
}

// ---------------- norms of the two scorers ----------------
__global__ void norm_kernel(const float* __restrict__ s0, const float* __restrict__ s1,
                            float* __restrict__ norms) {
    __shared__ float red[128];
    int tid = threadIdx.x;  // 128 threads
    float a = s0[tid];
    red[tid] = a * a;
    __syncthreads();
    for (int off = 64; off > 0; off >>= 1) { if (tid < off) red[tid] += red[tid + off]; __syncthreads(); }
    if (tid == 0) norms[0] = sqrtf(red[0]);
    __syncthreads();
    float b = s1[tid];
    red[tid] = b * b;
    __syncthreads();
    for (int off = 64; off > 0; off >>= 1) { if (tid < off) red[tid] += red[tid + off]; __syncthreads(); }
    if (tid == 0) norms[1] = sqrtf(red[0]);
}

// ---------------- L0 scores for ALL t + topk histogram ----------------
// grid: (ceil(N/256), T_STEPS)
__global__ void scores_hist4_kernel(const float* __restrict__ node_embs, const float* __restrict__ scorer,
                                    const float* __restrict__ norms,
                                    const float* __restrict__ mask, float* __restrict__ scores4,
                                    int* __restrict__ ghist4, int N) {
    __shared__ float sc[FIN];
    if (threadIdx.x < FIN) sc[threadIdx.x] = scorer[threadIdx.x];
    __syncthreads();
    int t = blockIdx.y;
    int n = blockIdx.x * blockDim.x + threadIdx.x;
    if (n >= N) return;
    const float4* xr = (const float4*)(node_embs + ((size_t)t * N + n) * FIN);
    float acc = 0.f;
#pragma unroll 8
    for (int k4 = 0; k4 < FIN / 4; k4++) {
        float4 v = xr[k4];
        acc += v.x * sc[k4 * 4] + v.y * sc[k4 * 4 + 1] + v.z * sc[k4 * 4 + 2] + v.w * sc[k4 * 4 + 3];
    }
    float s = acc / norms[0] + mask[(size_t)t * N + n];
    scores4[(size_t)t * N + n] = s;
    atomicAdd(&ghist4[t * NBINS + (key_of(s) >> BINSHIFT)], 1);
}

// ---------------- parallel top-k collect: each block re-derives critical bin ----------------
// grid: (196, ntasks). task strides: scores N, ghist NBINS, cnts 2, gt 128, eq EQCAP
__global__ void __launch_bounds__(256)
topk_collect_kernel(const float* __restrict__ scores_b, const int* __restrict__ ghist_b,
                    int* __restrict__ cnts_b, int* __restrict__ gt_idx_b, float* __restrict__ gt_val_b,
                    int* __restrict__ eq_idx_b, float* __restrict__ eq_val_b, int N, int K) {
    __shared__ int h[NBINS];
    __shared__ int part[256];
    __shared__ int s_bin;
    int tid = threadIdx.x;
    int task = blockIdx.y;
    const int* gh = ghist_b + (size_t)task * NBINS;
    for (int i = tid; i < NBINS; i += 256) h[i] = gh[i];
    __syncthreads();
    int s = 0;
#pragma unroll
    for (int i = 0; i < NBINS / 256; i++) s += h[tid * (NBINS / 256) + i];
    part[tid] = s;
    __syncthreads();
    for (int off = 1; off < 256; off <<= 1) {
        int v = (tid + off < 256) ? part[tid + off] : 0;
        __syncthreads();
        part[tid] += v;
        __syncthreads();
    }
    {
        int run = (tid == 255) ? 0 : part[tid + 1];
        const int CH = NBINS / 256;
        for (int b = tid * CH + CH - 1; b >= tid * CH; b--) {
            int Sb = run + h[b];
            if (Sb >= K && run < K) s_bin = b;
            run = Sb;
        }
    }
    __syncthreads();
    int bin = s_bin;
    const float* scores = scores_b + (size_t)task * N;
    int* cg = cnts_b + task * 2;
    for (int n = blockIdx.x * 256 + tid; n < N; n += gridDim.x * 256) {
        float sc = scores[n];
        unsigned int key = key_of(sc);
        int kb = (int)(key >> BINSHIFT);
        if (kb > bin) {
            int p = atomicAdd(&cg[0], 1);
            gt_idx_b[task * 128 + p] = n; gt_val_b[task * 128 + p] = sc;
        } else if (kb == bin) {
            int p = atomicAdd(&cg[1], 1);
            if (p < EQCAP) { eq_idx_b[task * EQCAP + p] = n; eq_val_b[task * EQCAP + p] = sc; }
        }
    }
}

// ---------------- finish: exact rank + sort + z build; self-zero ghist & cnts ----------------
// grid: (ntasks). need = K - cnt_gt. z[r*K+j] = X[idx_j*FIN+r]*tanh(val_j)
template <int K>
__global__ void __launch_bounds__(1024)
topk_finish_kernel(int* __restrict__ ghist_b, int* __restrict__ cnts_b,
                   const int* __restrict__ gt_idx_b, const float* __restrict__ gt_val_b,
                   const int* __restrict__ eq_idx_b, const float* __restrict__ eq_val_b,
                   const float* __restrict__ X_b, float* __restrict__ z_b, int N) {
    __shared__ int sidx[K];
    __shared__ float sval[K];
    __shared__ unsigned int ek[EQCAP];
    __shared__ int ei[EQCAP];
    __shared__ int out_idx[K];
    __shared__ float out_tanh[K];
    int tid = threadIdx.x;
    int task = blockIdx.x;
    int* cg = cnts_b + task * 2;
    int g = cg[0];
    int m = min(cg[1], EQCAP);
    int need = K - g;
    const int* gt_idx = gt_idx_b + task * 128;
    const float* gt_val = gt_val_b + task * 128;
    const int* eq_idx = eq_idx_b + task * EQCAP;
    const float* eq_val = eq_val_b + task * EQCAP;
    const float* X = X_b + (size_t)task * N * FIN;
    float* z = z_b + (size_t)task * FIN * K;

    for (int i = tid; i < g; i += 1024) { sidx[i] = gt_idx[i]; sval[i] = gt_val[i]; }
    for (int i = tid; i < m; i += 1024) { ek[i] = key_of(eq_val[i]); ei[i] = eq_idx[i]; }
    __syncthreads();
    for (int i = tid; i < m; i += 1024) {
        int myi = ei[i];
        unsigned int myk = ek[i];
        int rank = 0;
        for (int j = 0; j < m; j++)
            rank += (ek[j] > myk) || (ek[j] == myk && ei[j] < myi);
        if (rank < need) { sidx[g + rank] = myi; sval[g + rank] = eq_val[i]; }
    }
    __syncthreads();
    if (tid < K) {
        float v = sval[tid];
        int id = sidx[tid];
        unsigned int myk = key_of(v);
        int rank = 0;
        for (int j = 0; j < K; j++) {
            unsigned int kj = key_of(sval[j]);
            rank += (kj > myk) || (kj == myk && sidx[j] < id);
        }
        out_idx[rank] = id;
        out_tanh[rank] = tanhf(v);
    }
    // self-zero for next reuse
    int* gh = ghist_b + (size_t)task * NBINS;
    for (int i = tid; i < NBINS; i += 1024) gh[i] = 0;
    if (tid == 0) { cg[0] = 0; cg[1] = 0; }
    __syncthreads();
    for (int i = tid; i < K * FIN; i += 1024) {
        int j = i >> 7;        // / FIN
        int r = i & 127;       // % FIN
        z[r * K + j] = X[(size_t)out_idx[j] * FIN + r] * out_tanh[j];
    }
}

// ---------------- fused GRU: upd/rst/hcap/Qn in one kernel ----------------
template <int COLS>
__global__ void __launch_bounds__(256)
gru_fused_kernel(const float* __restrict__ z, const float* __restrict__ Q,
                 const float* __restrict__ Wu, const float* __restrict__ Uu, const float* __restrict__ Bu,
                 const float* __restrict__ Wr, const float* __restrict__ Ur, const float* __restrict__ Br,
                 const float* __restrict__ Wh, const float* __restrict__ Uh, const float* __restrict__ Bh,
                 float* __restrict__ Qn) {
    __shared__ float zc[128][8];
    __shared__ float qc[128][8];
    __shared__ float rq[128][8];
    __shared__ float ul[128][8];
    int tid = threadIdx.x;
    int c0 = blockIdx.x * 8;
    for (int i = tid; i < 1024; i += 256) {
        int r = i >> 3, c = i & 7;
        zc[r][c] = z[r * COLS + c0 + c];
        qc[r][c] = Q[r * COLS + c0 + c];
    }
    __syncthreads();
#pragma unroll
    for (int e = 0; e < 4; e++) {
        int idx = tid + 256 * e;
        int r = idx >> 3, c = idx & 7;
        float au = Bu[r * COLS + c0 + c], ar = Br[r * COLS + c0 + c];
        for (int k = 0; k < 128; k++) {
            float zz = zc[k][c], qq = qc[k][c];
            au += Wu[r * 128 + k] * zz + Uu[r * 128 + k] * qq;
            ar += Wr[r * 128 + k] * zz + Ur[r * 128 + k] * qq;
        }
        ul[r][c] = sigmoidf_(au);
        rq[r][c] = sigmoidf_(ar) * qc[r][c];
    }
    __syncthreads();
#pragma unroll
    for (int e = 0; e < 4; e++) {
        int idx = tid + 256 * e;
        int r = idx >> 3, c = idx & 7;
        float s = Bh[r * COLS + c0 + c];
        for (int k = 0; k < 128; k++) {
            s += Wh[r * 128 + k] * zc[k][c] + Uh[r * 128 + k] * rq[k][c];
        }
        float h = tanhf(s);
        float u = ul[r][c];
        Qn[r * COLS + c0 + c] = (1.f - u) * qc[r][c] + u * h;
    }
}

// ---------------- XW = X @ Qn -> fp32 or bf16 out ----------------
template <int COLS, bool BF16>
__global__ void __launch_bounds__(256)
xw_kernel(const float* __restrict__ X, const float* __restrict__ Qn,
          void* __restrict__ outp, int N) {
    constexpr int TPR = COLS / 4;
    constexpr int RPG = 256 / TPR;
    constexpr int RPB = RPG * 4;
    __shared__ float4 qs[128 * TPR];
    for (int i = threadIdx.x; i < 128 * TPR; i += 256) qs[i] = ((const float4*)Qn)[i];
    __syncthreads();
    int lane_c = threadIdx.x % TPR;
    int rloc = threadIdx.x / TPR;
    int base = blockIdx.x * RPB;
    int rows[4];
    float4 acc[4];
#pragma unroll
    for (int j = 0; j < 4; j++) {
        rows[j] = base + rloc + j * RPG;
        acc[j] = make_float4(0.f, 0.f, 0.f, 0.f);
    }
    int nc[4];
#pragma unroll
    for (int j = 0; j < 4; j++) nc[j] = min(rows[j], N - 1);

    for (int k4 = 0; k4 < 32; k4++) {
        float4 q0 = qs[(k4 * 4 + 0) * TPR + lane_c];
        float4 q1 = qs[(k4 * 4 + 1) * TPR + lane_c];
        float4 q2 = qs[(k4 * 4 + 2) * TPR + lane_c];
        float4 q3 = qs[(k4 * 4 + 3) * TPR + lane_c];
#pragma unroll
        for (int j = 0; j < 4; j++) {
            float4 xv = ((const float4*)(X + (size_t)nc[j] * FIN))[k4];
            acc[j].x += xv.x * q0.x + xv.y * q1.x + xv.z * q2.x + xv.w * q3.x;
            acc[j].y += xv.x * q0.y + xv.y * q1.y + xv.z * q2.y + xv.w * q3.y;
            acc[j].z += xv.x * q0.z + xv.y * q1.z + xv.z * q2.z + xv.w * q3.z;
            acc[j].w += xv.x * q0.w + xv.y * q1.w + xv.z * q2.w + xv.w * q3.w;
        }
    }
#pragma unroll
    for (int j = 0; j < 4; j++) {
        if (rows[j] < N) {
            if (BF16) {
                ushort4 o;
                o.x = f2bf(acc[j].x); o.y = f2bf(acc[j].y);
                o.z = f2bf(acc[j].z); o.w = f2bf(acc[j].w);
                ((ushort4*)((unsigned short*)outp + (size_t)rows[j] * COLS))[lane_c] = o;
            } else {
                ((float4*)((float*)outp + (size_t)rows[j] * COLS))[lane_c] = acc[j];
            }
        }
    }
}

// ---------------- batched CSR build over all 4 timesteps ----------------
__global__ void hist4_kernel(const int* __restrict__ dst, int* __restrict__ hist4, int E) {
    int e = blockIdx.x * blockDim.x + threadIdx.x;
    if (e >= E) return;
    int t = blockIdx.y;
    atomicAdd(&hist4[t * NNODES + dst[(size_t)t * E + e]], 1);
}

__global__ void __launch_bounds__(256)
scanA_kernel(const int* __restrict__ hist, int* __restrict__ incl, int* __restrict__ bsum, int M) {
    __shared__ int sh[256];
    int gid = blockIdx.x * 256 + threadIdx.x;
    int v = (gid < M) ? hist[gid] : 0;
    sh[threadIdx.x] = v;
    __syncthreads();
    for (int off = 1; off < 256; off <<= 1) {
        int u = (threadIdx.x >= off) ? sh[threadIdx.x - off] : 0;
        __syncthreads();
        sh[threadIdx.x] += u;
        __syncthreads();
    }
    if (gid < M) incl[gid] = sh[threadIdx.x];
    if (threadIdx.x == 255) bsum[blockIdx.x] = sh[255];
}

__global__ void __launch_bounds__(1024)
scanB_kernel(int* __restrict__ bsum, int nb) {
    __shared__ int sh[1024];
    int tid = threadIdx.x;
    int v = (tid < nb) ? bsum[tid] : 0;
    sh[tid] = v;
    __syncthreads();
    for (int off = 1; off < 1024; off <<= 1) {
        int u = (tid >= off) ? sh[tid - off] : 0;
        __syncthreads();
        sh[tid] += u;
        __syncthreads();
    }
    if (tid < nb) bsum[tid] = (tid == 0) ? 0 : sh[tid - 1];
}

__global__ void __launch_bounds__(256)
scanC_kernel(const int* __restrict__ hist, const int* __restrict__ incl,
             const int* __restrict__ bsum, int* __restrict__ row_ptr,
             int* __restrict__ cursor, int M) {
    int gid = blockIdx.x * 256 + threadIdx.x;
    if (gid < M) {
        int inc = incl[gid] + bsum[gid / 256];
        int ex = inc - hist[gid];
        row_ptr[gid] = ex;
        cursor[gid] = ex;
        if (gid == M - 1) row_ptr[M] = inc;
    }
}

// dst-range-sharded scatter: blockIdx.x&7 selects dst shard; CSR positions for a
// dst shard are CONTIGUOUS -> each sedge region written by one block-class
// (XCD-local under the %8 heuristic) so L2 lines coalesce before write-back.
__global__ void bucket4_kernel(const int* __restrict__ src, const int* __restrict__ dst,
                               const float* __restrict__ w, int* __restrict__ cursor,
                               int2* __restrict__ sedge, int E) {
    int bx = blockIdx.x;
    int shard = bx & 7;
    int e = (bx >> 3) * 256 + threadIdx.x;
    if (e >= E) return;
    int t = blockIdx.y;
    size_t ge = (size_t)t * E + e;
    int d = dst[ge];
    if (d / DSHARD != shard) return;
    int pos = atomicAdd(&cursor[t * NNODES + d], 1);
    int2 pk;
    pk.x = src[ge];
    pk.y = __float_as_int(w[ge]);
    sedge[pos] = pk;
}

// ---------------- CSR aggregation: out[d] = relu(sum w_e * XW[src_e]) ----------------
// 4-deep edge unroll with independent accumulators: 4 gathers in flight per group
// (mean degree ~8; the serial per-edge vmcnt chain was the R7 latency bottleneck).
template <int COLS, bool SCORE, bool BF16>
__global__ void __launch_bounds__(256)
agg_kernel(const void* __restrict__ XWp, const int* __restrict__ row_ptr,
           const int2* __restrict__ sedge,
           float* __restrict__ out, int N,
           const float* __restrict__ scorer, const float* __restrict__ norms,
           const float* __restrict__ mask, float* __restrict__ scores, int* __restrict__ ghist) {
    constexpr int TPN = COLS / 4;
    constexpr int NPB = 256 / TPN;
    int node = blockIdx.x * NPB + threadIdx.x / TPN;
    int lane = threadIdx.x % TPN;
    if (node >= N) return;
    int beg = row_ptr[node], end = row_ptr[node + 1];
    float4 a0 = make_float4(0.f, 0.f, 0.f, 0.f);
    float4 a1 = a0, a2 = a0, a3 = a0;
    int i = beg;
    for (; i + 4 <= end; i += 4) {
        int2 p0 = sedge[i], p1 = sedge[i + 1], p2 = sedge[i + 2], p3 = sedge[i + 3];
        if (BF16) {
            const unsigned short* XW = (const unsigned short*)XWp;
            ushort4 v0 = ((const ushort4*)(XW + (size_t)p0.x * COLS))[lane];
            ushort4 v1 = ((const ushort4*)(XW + (size_t)p1.x * COLS))[lane];
            ushort4 v2 = ((const ushort4*)(XW + (size_t)p2.x * COLS))[lane];
            ushort4 v3 = ((const ushort4*)(XW + (size_t)p3.x * COLS))[lane];
            float w0 = __int_as_float(p0.y), w1 = __int_as_float(p1.y);
            float w2 = __int_as_float(p2.y), w3 = __int_as_float(p3.y);
            a0.x += bf2f(v0.x) * w0; a0.y += bf2f(v0.y) * w0; a0.z += bf2f(v0.z) * w0; a0.w += bf2f(v0.w) * w0;
            a1.x += bf2f(v1.x) * w1; a1.y += bf2f(v1.y) * w1; a1.z += bf2f(v1.z) * w1; a1.w += bf2f(v1.w) * w1;
            a2.x += bf2f(v2.x) * w2; a2.y += bf2f(v2.y) * w2; a2.z += bf2f(v2.z) * w2; a2.w += bf2f(v2.w) * w2;
            a3.x += bf2f(v3.x) * w3; a3.y += bf2f(v3.y) * w3; a3.z += bf2f(v3.z) * w3; a3.w += bf2f(v3.w) * w3;
        } else {
            const float* XW = (const float*)XWp;
            float4 v0 = ((const float4*)(XW + (size_t)p0.x * COLS))[lane];
            float4 v1 = ((const float4*)(XW + (size_t)p1.x * COLS))[lane];
            float4 v2 = ((const float4*)(XW + (size_t)p2.x * COLS))[lane];
            float4 v3 = ((const float4*)(XW + (size_t)p3.x * COLS))[lane];
            float w0 = __int_as_float(p0.y), w1 = __int_as_float(p1.y);
            float w2 = __int_as_float(p2.y), w3 = __int_as_float(p3.y);
            a0.x += v0.x * w0; a0.y += v0.y * w0; a0.z += v0.z * w0; a0.w += v0.w * w0;
            a1.x += v1.x * w1; a1.y += v1.y * w1; a1.z += v1.z * w1; a1.w += v1.w * w1;
            a2.x += v2.x * w2; a2.y += v2.y * w2; a2.z += v2.z * w2; a2.w += v2.w * w2;
            a3.x += v3.x * w3; a3.y += v3.y * w3; a3.z += v3.z * w3; a3.w += v3.w * w3;
        }
    }
    for (; i < end; i++) {
        int2 pk = sedge[i];
        float wt = __int_as_float(pk.y);
        if (BF16) {
            ushort4 v = ((const ushort4*)((const unsigned short*)XWp + (size_t)pk.x * COLS))[lane];
            a0.x += bf2f(v.x) * wt; a0.y += bf2f(v.y) * wt;
            a0.z += bf2f(v.z) * wt; a0.w += bf2f(v.w) * wt;
        } else {
            float4 v = ((const float4*)((const float*)XWp + (size_t)pk.x * COLS))[lane];
            a0.x += v.x * wt; a0.y += v.y * wt; a0.z += v.z * wt; a0.w += v.w * wt;
        }
    }
    float4 acc;
    acc.x = (a0.x + a1.x) + (a2.x + a3.x);
    acc.y = (a0.y + a1.y) + (a2.y + a3.y);
    acc.z = (a0.z + a1.z) + (a2.z + a3.z);
    acc.w = (a0.w + a1.w) + (a2.w + a3.w);
    acc.x = fmaxf(acc.x, 0.f); acc.y = fmaxf(acc.y, 0.f);
    acc.z = fmaxf(acc.z, 0.f); acc.w = fmaxf(acc.w, 0.f);
    ((float4*)(out + (size_t)node * COLS))[lane] = acc;
    if (SCORE) {
        float4 sc4 = ((const float4*)scorer)[lane];
        float partial = acc.x * sc4.x + acc.y * sc4.y + acc.z * sc4.z + acc.w * sc4.w;
#pragma unroll
        for (int off = TPN / 2; off > 0; off >>= 1) partial += __shfl_xor(partial, off, TPN);
        if (lane == 0) {
            float s = partial / norms[1] + mask[node];
            scores[node] = s;
            atomicAdd(&ghist[key_of(s) >> BINSHIFT], 1);
        }
    }
}

extern "C" void kernel_launch(void* const* d_in, const int* in_sizes, int n_in,
                              void* d_out, int out_size, void* d_ws, size_t ws_size,
                              hipStream_t stream) {
    const float* node_embs   = (const float*)d_in[0];
    const float* mask        = (const float*)d_in[1];
    const int*   edge_src    = (const int*)d_in[2];
    const int*   edge_dst    = (const int*)d_in[3];
    const float* edge_weight = (const float*)d_in[4];
    const float* gcn_w0      = (const float*)d_in[5];
    const float* gcn_w1      = (const float*)d_in[6];
    const float* l0p[10];
    const float* l1p[10];
    for (int i = 0; i < 10; i++) l0p[i] = (const float*)d_in[7 + i];
    for (int i = 0; i < 10; i++) l1p[i] = (const float*)d_in[17 + i];
    // l*p: 0=Wu 1=Uu 2=Bu 3=Wr 4=Ur 5=Br 6=Wh 7=Uh 8=Bh 9=scorer

    char* ws = (char*)d_ws;
    size_t off = 0;
    auto alloc = [&](size_t bytes) -> void* {
        void* p = ws + off;
        off += (bytes + 255) / 256 * 256;
        return p;
    };
    float* XWbuf  = (float*)alloc((size_t)NNODES * 128 * 4);   // fp32 L0 / bf16 L1 (reuse)
    float* h1buf  = (float*)alloc((size_t)NNODES * 128 * 4);
    float* scores4= (float*)alloc((size_t)4 * NNODES * 4);     // L0 scores (all t)
    float* scores1= (float*)alloc((size_t)NNODES * 4);         // L1 scores (per t)
    float* z0buf  = (float*)alloc((size_t)4 * 128 * 128 * 4);  // L0 z (all t)
    float* z1buf  = (float*)alloc(128 * 64 * 4);
    float* Q0a    = (float*)alloc(128 * 128 * 4);
    float* Q0b    = (float*)alloc(128 * 128 * 4);
    float* Q1a    = (float*)alloc(128 * 64 * 4);
    float* Q1b    = (float*)alloc(128 * 64 * 4);
    float* norms  = (float*)alloc(64);
    // combined zeroed region: hist4[4N] + ghist0[4*NBINS] + ghist1[NBINS] + cnts[64]
    int* hist4    = (int*)alloc(((size_t)4 * NNODES + 5 * NBINS + 64) * 4);
    int* ghist0   = hist4 + 4 * NNODES;
    int* ghist1   = ghist0 + 4 * NBINS;
    int* cnts     = ghist1 + NBINS;      // 4 tasks x 2 (L1 reuses slots 0,1)
    int* incl4    = (int*)alloc((size_t)4 * NNODES * 4);
    int* bsumb    = (int*)alloc(1024 * 4);
    int* rowp4    = (int*)alloc(((size_t)4 * NNODES + 1) * 4);
    int* cursor4  = (int*)alloc((size_t)4 * NNODES * 4);
    int2* sedge4  = (int2*)alloc((size_t)4 * NEDGES * 8);
    int*   gt_idx = (int*)alloc((size_t)4 * 128 * 4);
    float* gt_val = (float*)alloc((size_t)4 * 128 * 4);
    int*   eq_idx = (int*)alloc((size_t)4 * EQCAP * 4);
    float* eq_val = (float*)alloc((size_t)4 * EQCAP * 4);

    hipMemcpyAsync(Q0a, gcn_w0, 128 * 128 * 4, hipMemcpyDeviceToDevice, stream);
    hipMemcpyAsync(Q1a, gcn_w1, 128 * 64 * 4, hipMemcpyDeviceToDevice, stream);
    hipMemsetAsync(hist4, 0, ((size_t)4 * NNODES + 5 * NBINS + 64) * 4, stream);
    norm_kernel<<<1, 128, 0, stream>>>(l0p[9], l1p[9], norms);

    const int M4 = 4 * NNODES;
    const int NB4 = (M4 + 255) / 256;          // 782
    const int NB = (NNODES + 255) / 256;       // 196
    const int EB = (NEDGES + 255) / 256;       // 1563

    // ---- batched CSR build for all 4 timesteps ----
    hist4_kernel<<<dim3(EB, 4), 256, 0, stream>>>(edge_dst, hist4, NEDGES);
    scanA_kernel<<<NB4, 256, 0, stream>>>(hist4, incl4, bsumb, M4);
    scanB_kernel<<<1, 1024, 0, stream>>>(bsumb, NB4);
    scanC_kernel<<<NB4, 256, 0, stream>>>(hist4, incl4, bsumb, rowp4, cursor4, M4);
    bucket4_kernel<<<dim3(EB * 8, 4), 256, 0, stream>>>(edge_src, edge_dst, edge_weight, cursor4, sedge4, NEDGES);

    // ---- L0 scores + top-k + z for ALL t (input-only dependence) ----
    scores_hist4_kernel<<<dim3(NB, 4), 256, 0, stream>>>(node_embs, l0p[9], norms, mask, scores4, ghist0, NNODES);
    topk_collect_kernel<<<dim3(NB, 4), 256, 0, stream>>>(scores4, ghist0, cnts, gt_idx, gt_val, eq_idx, eq_val, NNODES, 128);
    topk_finish_kernel<128><<<4, 1024, 0, stream>>>(ghist0, cnts, gt_idx, gt_val, eq_idx, eq_val, node_embs, z0buf, NNODES);

    float* Q0cur = Q0a; float* Q0nxt = Q0b;
    float* Q1cur = Q1a; float* Q1nxt = Q1b;

    for (int t = 0; t < T_STEPS; t++) {
        const float* X0 = node_embs + (size_t)t * NNODES * 128;
        const float* mk = mask + (size_t)t * NNODES;
        const int* rp_t = rowp4 + (size_t)t * NNODES;

        // ---- layer 0 (fp32 XW: h1 feeds layer-1 top-k selection, must stay exact) ----
        gru_fused_kernel<128><<<16, 256, 0, stream>>>(z0buf + (size_t)t * 128 * 128, Q0cur,
            l0p[0], l0p[1], l0p[2], l0p[3], l0p[4], l0p[5], l0p[6], l0p[7], l0p[8], Q0nxt);
        xw_kernel<128, false><<<(NNODES + 31) / 32, 256, 0, stream>>>(X0, Q0nxt, XWbuf, NNODES);
        agg_kernel<128, true, false><<<(NNODES + 7) / 8, 256, 0, stream>>>(XWbuf, rp_t, sedge4, h1buf, NNODES,
            l1p[9], norms, mk, scores1, ghist1);

        // ---- layer 1 (h1buf relu'd; scores1/ghist1 from agg; bf16 XW: output-only path) ----
        topk_collect_kernel<<<dim3(NB, 1), 256, 0, stream>>>(scores1, ghist1, cnts, gt_idx, gt_val, eq_idx, eq_val, NNODES, 64);
        topk_finish_kernel<64><<<1, 1024, 0, stream>>>(ghist1, cnts, gt_idx, gt_val, eq_idx, eq_val, h1buf, z1buf, NNODES);
        gru_fused_kernel<64><<<8, 256, 0, stream>>>(z1buf, Q1cur,
            l1p[0], l1p[1], l1p[2], l1p[3], l1p[4], l1p[5], l1p[6], l1p[7], l1p[8], Q1nxt);
        xw_kernel<64, true><<<(NNODES + 63) / 64, 256, 0, stream>>>(h1buf, Q1nxt, XWbuf, NNODES);
        float* out_t = (float*)d_out + (size_t)t * NNODES * 64;
        agg_kernel<64, false, true><<<(NNODES + 15) / 16, 256, 0, stream>>>(XWbuf, rp_t, sedge4, out_t, NNODES,
            nullptr, nullptr, nullptr, nullptr, nullptr);

        float* tmp;
        tmp = Q0cur; Q0cur = Q0nxt; Q0nxt = tmp;
        tmp = Q1cur; Q1cur = Q1nxt; Q1nxt = tmp;
    }
}

// Round 9
// 1229.278 us; speedup vs baseline: 1.5014x; 1.2998x over previous
//
#include <hip/hip_runtime.h>
#include <math.h>

#define T_STEPS 4
#define NNODES 50000
#define NEDGES 400000
#define FIN 128   // input feature dim for both layers
#define NBINS 8192
#define BINSHIFT 19  // 32-13
#define EQCAP 4096
#define DSHARD 6250  // NNODES/8

__device__ __forceinline__ float sigmoidf_(float x) { return 1.0f / (1.0f + __expf(-x)); }

__device__ __forceinline__ unsigned int key_of(float s) {
    unsigned int u = __float_as_uint(s);
    return (u & 0x80000000u) ? ~u : (u | 0x80000000u);
}

__device__ __forceinline__ unsigned short f2bf(float f) {
    unsigned int u = __float_as_uint(f);
    unsigned int r = (u + 0x7FFFu + ((u >> 16) & 1u)) >> 16;
    return (unsigned short)r;
}
__device__ __forceinline__ float bf2f(unsigned short h) {
    return __uint_as_float(((unsigned int)h) << 16);
}

// ---------------- norms of the two scorers ----------------
__global__ void norm_kernel(const float* __restrict__ s0, const float* __restrict__ s1,
                            float* __restrict__ norms) {
    __shared__ float red[128];
    int tid = threadIdx.x;  // 128 threads
    float a = s0[tid];
    red[tid] = a * a;
    __syncthreads();
    for (int off = 64; off > 0; off >>= 1) { if (tid < off) red[tid] += red[tid + off]; __syncthreads(); }
    if (tid == 0) norms[0] = sqrtf(red[0]);
    __syncthreads();
    float b = s1[tid];
    red[tid] = b * b;
    __syncthreads();
    for (int off = 64; off > 0; off >>= 1) { if (tid < off) red[tid] += red[tid + off]; __syncthreads(); }
    if (tid == 0) norms[1] = sqrtf(red[0]);
}

// ---------------- L0 scores for ALL t + topk histogram ----------------
// grid: (ceil(N/256), T_STEPS)
__global__ void scores_hist4_kernel(const float* __restrict__ node_embs, const float* __restrict__ scorer,
                                    const float* __restrict__ norms,
                                    const float* __restrict__ mask, float* __restrict__ scores4,
                                    int* __restrict__ ghist4, int N) {
    __shared__ float sc[FIN];
    if (threadIdx.x < FIN) sc[threadIdx.x] = scorer[threadIdx.x];
    __syncthreads();
    int t = blockIdx.y;
    int n = blockIdx.x * blockDim.x + threadIdx.x;
    if (n >= N) return;
    const float4* xr = (const float4*)(node_embs + ((size_t)t * N + n) * FIN);
    float acc = 0.f;
#pragma unroll 8
    for (int k4 = 0; k4 < FIN / 4; k4++) {
        float4 v = xr[k4];
        acc += v.x * sc[k4 * 4] + v.y * sc[k4 * 4 + 1] + v.z * sc[k4 * 4 + 2] + v.w * sc[k4 * 4 + 3];
    }
    float s = acc / norms[0] + mask[(size_t)t * N + n];
    scores4[(size_t)t * N + n] = s;
    atomicAdd(&ghist4[t * NBINS + (key_of(s) >> BINSHIFT)], 1);
}

// ---------------- parallel top-k collect: each block re-derives critical bin ----------------
// grid: (196, ntasks). task strides: scores N, ghist NBINS, cnts 2, gt 128, eq EQCAP
__global__ void __launch_bounds__(256)
topk_collect_kernel(const float* __restrict__ scores_b, const int* __restrict__ ghist_b,
                    int* __restrict__ cnts_b, int* __restrict__ gt_idx_b, float* __restrict__ gt_val_b,
                    int* __restrict__ eq_idx_b, float* __restrict__ eq_val_b, int N, int K) {
    __shared__ int h[NBINS];
    __shared__ int part[256];
    __shared__ int s_bin;
    int tid = threadIdx.x;
    int task = blockIdx.y;
    const int* gh = ghist_b + (size_t)task * NBINS;
    for (int i = tid; i < NBINS; i += 256) h[i] = gh[i];
    __syncthreads();
    int s = 0;
#pragma unroll
    for (int i = 0; i < NBINS / 256; i++) s += h[tid * (NBINS / 256) + i];
    part[tid] = s;
    __syncthreads();
    for (int off = 1; off < 256; off <<= 1) {
        int v = (tid + off < 256) ? part[tid + off] : 0;
        __syncthreads();
        part[tid] += v;
        __syncthreads();
    }
    {
        int run = (tid == 255) ? 0 : part[tid + 1];
        const int CH = NBINS / 256;
        for (int b = tid * CH + CH - 1; b >= tid * CH; b--) {
            int Sb = run + h[b];
            if (Sb >= K && run < K) s_bin = b;
            run = Sb;
        }
    }
    __syncthreads();
    int bin = s_bin;
    const float* scores = scores_b + (size_t)task * N;
    int* cg = cnts_b + task * 2;
    for (int n = blockIdx.x * 256 + tid; n < N; n += gridDim.x * 256) {
        float sc = scores[n];
        unsigned int key = key_of(sc);
        int kb = (int)(key >> BINSHIFT);
        if (kb > bin) {
            int p = atomicAdd(&cg[0], 1);
            gt_idx_b[task * 128 + p] = n; gt_val_b[task * 128 + p] = sc;
        } else if (kb == bin) {
            int p = atomicAdd(&cg[1], 1);
            if (p < EQCAP) { eq_idx_b[task * EQCAP + p] = n; eq_val_b[task * EQCAP + p] = sc; }
        }
    }
}

// ---------------- finish: exact rank + sort + z build; self-zero ghist & cnts ----------------
// grid: (ntasks). need = K - cnt_gt. z[r*K+j] = X[idx_j*FIN+r]*tanh(val_j)
template <int K>
__global__ void __launch_bounds__(1024)
topk_finish_kernel(int* __restrict__ ghist_b, int* __restrict__ cnts_b,
                   const int* __restrict__ gt_idx_b, const float* __restrict__ gt_val_b,
                   const int* __restrict__ eq_idx_b, const float* __restrict__ eq_val_b,
                   const float* __restrict__ X_b, float* __restrict__ z_b, int N) {
    __shared__ int sidx[K];
    __shared__ float sval[K];
    __shared__ unsigned int ek[EQCAP];
    __shared__ int ei[EQCAP];
    __shared__ int out_idx[K];
    __shared__ float out_tanh[K];
    int tid = threadIdx.x;
    int task = blockIdx.x;
    int* cg = cnts_b + task * 2;
    int g = cg[0];
    int m = min(cg[1], EQCAP);
    int need = K - g;
    const int* gt_idx = gt_idx_b + task * 128;
    const float* gt_val = gt_val_b + task * 128;
    const int* eq_idx = eq_idx_b + task * EQCAP;
    const float* eq_val = eq_val_b + task * EQCAP;
    const float* X = X_b + (size_t)task * N * FIN;
    float* z = z_b + (size_t)task * FIN * K;

    for (int i = tid; i < g; i += 1024) { sidx[i] = gt_idx[i]; sval[i] = gt_val[i]; }
    for (int i = tid; i < m; i += 1024) { ek[i] = key_of(eq_val[i]); ei[i] = eq_idx[i]; }
    __syncthreads();
    for (int i = tid; i < m; i += 1024) {
        int myi = ei[i];
        unsigned int myk = ek[i];
        int rank = 0;
        for (int j = 0; j < m; j++)
            rank += (ek[j] > myk) || (ek[j] == myk && ei[j] < myi);
        if (rank < need) { sidx[g + rank] = myi; sval[g + rank] = eq_val[i]; }
    }
    __syncthreads();
    if (tid < K) {
        float v = sval[tid];
        int id = sidx[tid];
        unsigned int myk = key_of(v);
        int rank = 0;
        for (int j = 0; j < K; j++) {
            unsigned int kj = key_of(sval[j]);
            rank += (kj > myk) || (kj == myk && sidx[j] < id);
        }
        out_idx[rank] = id;
        out_tanh[rank] = tanhf(v);
    }
    // self-zero for reuse (cnts slots shared between L0 and L1 passes)
    int* gh = ghist_b + (size_t)task * NBINS;
    for (int i = tid; i < NBINS; i += 1024) gh[i] = 0;
    if (tid == 0) { cg[0] = 0; cg[1] = 0; }
    __syncthreads();
    for (int i = tid; i < K * FIN; i += 1024) {
        int j = i >> 7;        // / FIN
        int r = i & 127;       // % FIN
        z[r * K + j] = X[(size_t)out_idx[j] * FIN + r] * out_tanh[j];
    }
}

// ---------------- multi-step fused GRU: all T steps in one kernel ----------------
// Column-separable recurrence: block owns 8 columns, holds Q in LDS across steps.
// z_all: [T][128][COLS] (precomputed); Qn_all: [T][128][COLS] outputs.
template <int COLS>
__global__ void __launch_bounds__(256)
gru_multi_kernel(const float* __restrict__ Qinit, const float* __restrict__ z_all,
                 const float* __restrict__ Wu, const float* __restrict__ Uu, const float* __restrict__ Bu,
                 const float* __restrict__ Wr, const float* __restrict__ Ur, const float* __restrict__ Br,
                 const float* __restrict__ Wh, const float* __restrict__ Uh, const float* __restrict__ Bh,
                 float* __restrict__ Qn_all) {
    __shared__ float zc[128][8];
    __shared__ float qc[128][8];
    __shared__ float rq[128][8];
    __shared__ float ul[128][8];
    int tid = threadIdx.x;
    int c0 = blockIdx.x * 8;
    for (int i = tid; i < 1024; i += 256) {
        int r = i >> 3, c = i & 7;
        qc[r][c] = Qinit[r * COLS + c0 + c];
    }
    for (int t = 0; t < T_STEPS; t++) {
        __syncthreads();   // protect zc (prev step readers) + publish qc updates
        const float* z = z_all + (size_t)t * 128 * COLS;
        for (int i = tid; i < 1024; i += 256) {
            int r = i >> 3, c = i & 7;
            zc[r][c] = z[r * COLS + c0 + c];
        }
        __syncthreads();
#pragma unroll
        for (int e = 0; e < 4; e++) {
            int idx = tid + 256 * e;
            int r = idx >> 3, c = idx & 7;
            float au = Bu[r * COLS + c0 + c], ar = Br[r * COLS + c0 + c];
            for (int k = 0; k < 128; k++) {
                float zz = zc[k][c], qq = qc[k][c];
                au += Wu[r * 128 + k] * zz + Uu[r * 128 + k] * qq;
                ar += Wr[r * 128 + k] * zz + Ur[r * 128 + k] * qq;
            }
            ul[r][c] = sigmoidf_(au);
            rq[r][c] = sigmoidf_(ar) * qc[r][c];
        }
        __syncthreads();
        float* Qn = Qn_all + (size_t)t * 128 * COLS;
#pragma unroll
        for (int e = 0; e < 4; e++) {
            int idx = tid + 256 * e;
            int r = idx >> 3, c = idx & 7;
            float s = Bh[r * COLS + c0 + c];
            for (int k = 0; k < 128; k++) {
                s += Wh[r * 128 + k] * zc[k][c] + Uh[r * 128 + k] * rq[k][c];
            }
            float h = tanhf(s);
            float u = ul[r][c];
            float qn = (1.f - u) * qc[r][c] + u * h;
            Qn[r * COLS + c0 + c] = qn;
            qc[r][c] = qn;     // own element only; published at next loop-top barrier
        }
    }
}

// ---------------- XW(t) = X(t) @ Qn(t) -> fp32 or bf16, batched over t via blockIdx.y ----------------
template <int COLS, bool BF16>
__global__ void __launch_bounds__(256)
xw_kernel(const float* __restrict__ X_b, const float* __restrict__ Qn_all,
          void* __restrict__ outp, int N) {
    constexpr int TPR = COLS / 4;
    constexpr int RPG = 256 / TPR;
    constexpr int RPB = RPG * 4;
    int t = blockIdx.y;
    const float* X = X_b + (size_t)t * N * FIN;
    const float* Qn = Qn_all + (size_t)t * 128 * COLS;
    __shared__ float4 qs[128 * TPR];
    for (int i = threadIdx.x; i < 128 * TPR; i += 256) qs[i] = ((const float4*)Qn)[i];
    __syncthreads();
    int lane_c = threadIdx.x % TPR;
    int rloc = threadIdx.x / TPR;
    int base = blockIdx.x * RPB;
    int rows[4];
    float4 acc[4];
#pragma unroll
    for (int j = 0; j < 4; j++) {
        rows[j] = base + rloc + j * RPG;
        acc[j] = make_float4(0.f, 0.f, 0.f, 0.f);
    }
    int nc[4];
#pragma unroll
    for (int j = 0; j < 4; j++) nc[j] = min(rows[j], N - 1);

    for (int k4 = 0; k4 < 32; k4++) {
        float4 q0 = qs[(k4 * 4 + 0) * TPR + lane_c];
        float4 q1 = qs[(k4 * 4 + 1) * TPR + lane_c];
        float4 q2 = qs[(k4 * 4 + 2) * TPR + lane_c];
        float4 q3 = qs[(k4 * 4 + 3) * TPR + lane_c];
#pragma unroll
        for (int j = 0; j < 4; j++) {
            float4 xv = ((const float4*)(X + (size_t)nc[j] * FIN))[k4];
            acc[j].x += xv.x * q0.x + xv.y * q1.x + xv.z * q2.x + xv.w * q3.x;
            acc[j].y += xv.x * q0.y + xv.y * q1.y + xv.z * q2.y + xv.w * q3.y;
            acc[j].z += xv.x * q0.z + xv.y * q1.z + xv.z * q2.z + xv.w * q3.z;
            acc[j].w += xv.x * q0.w + xv.y * q1.w + xv.z * q2.w + xv.w * q3.w;
        }
    }
#pragma unroll
    for (int j = 0; j < 4; j++) {
        if (rows[j] < N) {
            if (BF16) {
                ushort4 o;
                o.x = f2bf(acc[j].x); o.y = f2bf(acc[j].y);
                o.z = f2bf(acc[j].z); o.w = f2bf(acc[j].w);
                ((ushort4*)((unsigned short*)outp + ((size_t)t * N + rows[j]) * COLS))[lane_c] = o;
            } else {
                ((float4*)((float*)outp + ((size_t)t * N + rows[j]) * COLS))[lane_c] = acc[j];
            }
        }
    }
}

// ---------------- batched CSR build over all 4 timesteps ----------------
__global__ void hist4_kernel(const int* __restrict__ dst, int* __restrict__ hist4, int E) {
    int e = blockIdx.x * blockDim.x + threadIdx.x;
    if (e >= E) return;
    int t = blockIdx.y;
    atomicAdd(&hist4[t * NNODES + dst[(size_t)t * E + e]], 1);
}

__global__ void __launch_bounds__(256)
scanA_kernel(const int* __restrict__ hist, int* __restrict__ incl, int* __restrict__ bsum, int M) {
    __shared__ int sh[256];
    int gid = blockIdx.x * 256 + threadIdx.x;
    int v = (gid < M) ? hist[gid] : 0;
    sh[threadIdx.x] = v;
    __syncthreads();
    for (int off = 1; off < 256; off <<= 1) {
        int u = (threadIdx.x >= off) ? sh[threadIdx.x - off] : 0;
        __syncthreads();
        sh[threadIdx.x] += u;
        __syncthreads();
    }
    if (gid < M) incl[gid] = sh[threadIdx.x];
    if (threadIdx.x == 255) bsum[blockIdx.x] = sh[255];
}

__global__ void __launch_bounds__(1024)
scanB_kernel(int* __restrict__ bsum, int nb) {
    __shared__ int sh[1024];
    int tid = threadIdx.x;
    int v = (tid < nb) ? bsum[tid] : 0;
    sh[tid] = v;
    __syncthreads();
    for (int off = 1; off < 1024; off <<= 1) {
        int u = (tid >= off) ? sh[tid - off] : 0;
        __syncthreads();
        sh[tid] += u;
        __syncthreads();
    }
    if (tid < nb) bsum[tid] = (tid == 0) ? 0 : sh[tid - 1];
}

__global__ void __launch_bounds__(256)
scanC_kernel(const int* __restrict__ hist, const int* __restrict__ incl,
             const int* __restrict__ bsum, int* __restrict__ row_ptr,
             int* __restrict__ cursor, int M) {
    int gid = blockIdx.x * 256 + threadIdx.x;
    if (gid < M) {
        int inc = incl[gid] + bsum[gid / 256];
        int ex = inc - hist[gid];
        row_ptr[gid] = ex;
        cursor[gid] = ex;
        if (gid == M - 1) row_ptr[M] = inc;
    }
}

// dst-range-sharded scatter (R7 win: keeps sedge writes XCD-local, lines coalesce)
__global__ void bucket4_kernel(const int* __restrict__ src, const int* __restrict__ dst,
                               const float* __restrict__ w, int* __restrict__ cursor,
                               int2* __restrict__ sedge, int E) {
    int bx = blockIdx.x;
    int shard = bx & 7;
    int e = (bx >> 3) * 256 + threadIdx.x;
    if (e >= E) return;
    int t = blockIdx.y;
    size_t ge = (size_t)t * E + e;
    int d = dst[ge];
    if (d / DSHARD != shard) return;
    int pos = atomicAdd(&cursor[t * NNODES + d], 1);
    int2 pk;
    pk.x = src[ge];
    pk.y = __float_as_int(w[ge]);
    sedge[pos] = pk;
}

// ---------------- CSR aggregation, batched over t via blockIdx.y ----------------
// out(t)[d] = relu(sum w_e * XW(t)[src_e]); SCORE also emits next-layer scores+hist per t.
template <int COLS, bool SCORE, bool BF16>
__global__ void __launch_bounds__(256)
agg_kernel(const void* __restrict__ XWp, const int* __restrict__ row_ptr4,
           const int2* __restrict__ sedge,
           float* __restrict__ out_b, int N,
           const float* __restrict__ scorer, const float* __restrict__ norms,
           const float* __restrict__ mask_b, float* __restrict__ scores_b, int* __restrict__ ghist_b) {
    constexpr int TPN = COLS / 4;
    constexpr int NPB = 256 / TPN;
    int t = blockIdx.y;
    int node = blockIdx.x * NPB + threadIdx.x / TPN;
    int lane = threadIdx.x % TPN;
    if (node >= N) return;
    const int* rp = row_ptr4 + (size_t)t * N;
    int beg = rp[node], end = rp[node + 1];
    size_t xwoff = (size_t)t * N * COLS;
    float4 a0 = make_float4(0.f, 0.f, 0.f, 0.f);
    float4 a1 = a0, a2 = a0, a3 = a0;
    int i = beg;
    for (; i + 4 <= end; i += 4) {
        int2 p0 = sedge[i], p1 = sedge[i + 1], p2 = sedge[i + 2], p3 = sedge[i + 3];
        if (BF16) {
            const unsigned short* XW = (const unsigned short*)XWp + xwoff;
            ushort4 v0 = ((const ushort4*)(XW + (size_t)p0.x * COLS))[lane];
            ushort4 v1 = ((const ushort4*)(XW + (size_t)p1.x * COLS))[lane];
            ushort4 v2 = ((const ushort4*)(XW + (size_t)p2.x * COLS))[lane];
            ushort4 v3 = ((const ushort4*)(XW + (size_t)p3.x * COLS))[lane];
            float w0 = __int_as_float(p0.y), w1 = __int_as_float(p1.y);
            float w2 = __int_as_float(p2.y), w3 = __int_as_float(p3.y);
            a0.x += bf2f(v0.x) * w0; a0.y += bf2f(v0.y) * w0; a0.z += bf2f(v0.z) * w0; a0.w += bf2f(v0.w) * w0;
            a1.x += bf2f(v1.x) * w1; a1.y += bf2f(v1.y) * w1; a1.z += bf2f(v1.z) * w1; a1.w += bf2f(v1.w) * w1;
            a2.x += bf2f(v2.x) * w2; a2.y += bf2f(v2.y) * w2; a2.z += bf2f(v2.z) * w2; a2.w += bf2f(v2.w) * w2;
            a3.x += bf2f(v3.x) * w3; a3.y += bf2f(v3.y) * w3; a3.z += bf2f(v3.z) * w3; a3.w += bf2f(v3.w) * w3;
        } else {
            const float* XW = (const float*)XWp + xwoff;
            float4 v0 = ((const float4*)(XW + (size_t)p0.x * COLS))[lane];
            float4 v1 = ((const float4*)(XW + (size_t)p1.x * COLS))[lane];
            float4 v2 = ((const float4*)(XW + (size_t)p2.x * COLS))[lane];
            float4 v3 = ((const float4*)(XW + (size_t)p3.x * COLS))[lane];
            float w0 = __int_as_float(p0.y), w1 = __int_as_float(p1.y);
            float w2 = __int_as_float(p2.y), w3 = __int_as_float(p3.y);
            a0.x += v0.x * w0; a0.y += v0.y * w0; a0.z += v0.z * w0; a0.w += v0.w * w0;
            a1.x += v1.x * w1; a1.y += v1.y * w1; a1.z += v1.z * w1; a1.w += v1.w * w1;
            a2.x += v2.x * w2; a2.y += v2.y * w2; a2.z += v2.z * w2; a2.w += v2.w * w2;
            a3.x += v3.x * w3; a3.y += v3.y * w3; a3.z += v3.z * w3; a3.w += v3.w * w3;
        }
    }
    for (; i < end; i++) {
        int2 pk = sedge[i];
        float wt = __int_as_float(pk.y);
        if (BF16) {
            const unsigned short* XW = (const unsigned short*)XWp + xwoff;
            ushort4 v = ((const ushort4*)(XW + (size_t)pk.x * COLS))[lane];
            a0.x += bf2f(v.x) * wt; a0.y += bf2f(v.y) * wt;
            a0.z += bf2f(v.z) * wt; a0.w += bf2f(v.w) * wt;
        } else {
            const float* XW = (const float*)XWp + xwoff;
            float4 v = ((const float4*)(XW + (size_t)pk.x * COLS))[lane];
            a0.x += v.x * wt; a0.y += v.y * wt; a0.z += v.z * wt; a0.w += v.w * wt;
        }
    }
    float4 acc;
    acc.x = (a0.x + a1.x) + (a2.x + a3.x);
    acc.y = (a0.y + a1.y) + (a2.y + a3.y);
    acc.z = (a0.z + a1.z) + (a2.z + a3.z);
    acc.w = (a0.w + a1.w) + (a2.w + a3.w);
    acc.x = fmaxf(acc.x, 0.f); acc.y = fmaxf(acc.y, 0.f);
    acc.z = fmaxf(acc.z, 0.f); acc.w = fmaxf(acc.w, 0.f);
    ((float4*)(out_b + ((size_t)t * N + node) * COLS))[lane] = acc;
    if (SCORE) {
        float4 sc4 = ((const float4*)scorer)[lane];
        float partial = acc.x * sc4.x + acc.y * sc4.y + acc.z * sc4.z + acc.w * sc4.w;
#pragma unroll
        for (int off = TPN / 2; off > 0; off >>= 1) partial += __shfl_xor(partial, off, TPN);
        if (lane == 0) {
            float s = partial / norms[1] + mask_b[(size_t)t * N + node];
            scores_b[(size_t)t * N + node] = s;
            atomicAdd(&ghist_b[t * NBINS + (key_of(s) >> BINSHIFT)], 1);
        }
    }
}

extern "C" void kernel_launch(void* const* d_in, const int* in_sizes, int n_in,
                              void* d_out, int out_size, void* d_ws, size_t ws_size,
                              hipStream_t stream) {
    const float* node_embs   = (const float*)d_in[0];
    const float* mask        = (const float*)d_in[1];
    const int*   edge_src    = (const int*)d_in[2];
    const int*   edge_dst    = (const int*)d_in[3];
    const float* edge_weight = (const float*)d_in[4];
    const float* gcn_w0      = (const float*)d_in[5];
    const float* gcn_w1      = (const float*)d_in[6];
    const float* l0p[10];
    const float* l1p[10];
    for (int i = 0; i < 10; i++) l0p[i] = (const float*)d_in[7 + i];
    for (int i = 0; i < 10; i++) l1p[i] = (const float*)d_in[17 + i];
    // l*p: 0=Wu 1=Uu 2=Bu 3=Wr 4=Ur 5=Br 6=Wh 7=Uh 8=Bh 9=scorer

    char* ws = (char*)d_ws;
    size_t off = 0;
    auto alloc = [&](size_t bytes) -> void* {
        void* p = ws + off;
        off += (bytes + 255) / 256 * 256;
        return p;
    };
    float* XW0buf = (float*)alloc((size_t)4 * NNODES * 128 * 4);          // fp32, all t (102 MB)
    float* h1buf  = (float*)alloc((size_t)4 * NNODES * 128 * 4);          // fp32, all t (102 MB)
    unsigned short* XW1buf = (unsigned short*)alloc((size_t)4 * NNODES * 64 * 2);  // bf16, all t
    float* scores4= (float*)alloc((size_t)4 * NNODES * 4);                // L0 scores (all t)
    float* scores1= (float*)alloc((size_t)4 * NNODES * 4);                // L1 scores (all t)
    float* z0buf  = (float*)alloc((size_t)4 * 128 * 128 * 4);
    float* z1buf  = (float*)alloc((size_t)4 * 128 * 64 * 4);
    float* Q0n    = (float*)alloc((size_t)4 * 128 * 128 * 4);
    float* Q1n    = (float*)alloc((size_t)4 * 128 * 64 * 4);
    float* norms  = (float*)alloc(64);
    // combined zeroed region: hist4[4N] + ghist0[4*NBINS] + ghist1[4*NBINS] + cnts[64]
    int* hist4    = (int*)alloc(((size_t)4 * NNODES + 8 * NBINS + 64) * 4);
    int* ghist0   = hist4 + 4 * NNODES;
    int* ghist1   = ghist0 + 4 * NBINS;
    int* cnts     = ghist1 + 4 * NBINS;
    int* incl4    = (int*)alloc((size_t)4 * NNODES * 4);
    int* bsumb    = (int*)alloc(1024 * 4);
    int* rowp4    = (int*)alloc(((size_t)4 * NNODES + 1) * 4);
    int* cursor4  = (int*)alloc((size_t)4 * NNODES * 4);
    int2* sedge4  = (int2*)alloc((size_t)4 * NEDGES * 8);
    int*   gt_idx = (int*)alloc((size_t)4 * 128 * 4);
    float* gt_val = (float*)alloc((size_t)4 * 128 * 4);
    int*   eq_idx = (int*)alloc((size_t)4 * EQCAP * 4);
    float* eq_val = (float*)alloc((size_t)4 * EQCAP * 4);

    hipMemsetAsync(hist4, 0, ((size_t)4 * NNODES + 8 * NBINS + 64) * 4, stream);
    norm_kernel<<<1, 128, 0, stream>>>(l0p[9], l1p[9], norms);

    const int M4 = 4 * NNODES;
    const int NB4 = (M4 + 255) / 256;          // 782
    const int NB = (NNODES + 255) / 256;       // 196
    const int EB = (NEDGES + 255) / 256;       // 1563

    // ---- batched CSR build for all 4 timesteps ----
    hist4_kernel<<<dim3(EB, 4), 256, 0, stream>>>(edge_dst, hist4, NEDGES);
    scanA_kernel<<<NB4, 256, 0, stream>>>(hist4, incl4, bsumb, M4);
    scanB_kernel<<<1, 1024, 0, stream>>>(bsumb, NB4);
    scanC_kernel<<<NB4, 256, 0, stream>>>(hist4, incl4, bsumb, rowp4, cursor4, M4);
    bucket4_kernel<<<dim3(EB * 8, 4), 256, 0, stream>>>(edge_src, edge_dst, edge_weight, cursor4, sedge4, NEDGES);

    // ---- L0: scores + top-k + z for ALL t (input-only dependence) ----
    scores_hist4_kernel<<<dim3(NB, 4), 256, 0, stream>>>(node_embs, l0p[9], norms, mask, scores4, ghist0, NNODES);
    topk_collect_kernel<<<dim3(NB, 4), 256, 0, stream>>>(scores4, ghist0, cnts, gt_idx, gt_val, eq_idx, eq_val, NNODES, 128);
    topk_finish_kernel<128><<<4, 1024, 0, stream>>>(ghist0, cnts, gt_idx, gt_val, eq_idx, eq_val, node_embs, z0buf, NNODES);

    // ---- L0 GRU recurrence (all t, one kernel), then batched XW + agg ----
    gru_multi_kernel<128><<<16, 256, 0, stream>>>(gcn_w0, z0buf,
        l0p[0], l0p[1], l0p[2], l0p[3], l0p[4], l0p[5], l0p[6], l0p[7], l0p[8], Q0n);
    xw_kernel<128, false><<<dim3((NNODES + 31) / 32, 4), 256, 0, stream>>>(node_embs, Q0n, XW0buf, NNODES);
    agg_kernel<128, true, false><<<dim3((NNODES + 7) / 8, 4), 256, 0, stream>>>(XW0buf, rowp4, sedge4, h1buf, NNODES,
        l1p[9], norms, mask, scores1, ghist1);

    // ---- L1: top-k for all t (h1+scores1 ready), GRU recurrence, batched XW + agg -> d_out ----
    topk_collect_kernel<<<dim3(NB, 4), 256, 0, stream>>>(scores1, ghist1, cnts, gt_idx, gt_val, eq_idx, eq_val, NNODES, 64);
    topk_finish_kernel<64><<<4, 1024, 0, stream>>>(ghist1, cnts, gt_idx, gt_val, eq_idx, eq_val, h1buf, z1buf, NNODES);
    gru_multi_kernel<64><<<8, 256, 0, stream>>>(gcn_w1, z1buf,
        l1p[0], l1p[1], l1p[2], l1p[3], l1p[4], l1p[5], l1p[6], l1p[7], l1p[8], Q1n);
    xw_kernel<64, true><<<dim3((NNODES + 63) / 64, 4), 256, 0, stream>>>(h1buf, Q1n, XW1buf, NNODES);
    agg_kernel<64, false, true><<<dim3((NNODES + 15) / 16, 4), 256, 0, stream>>>(XW1buf, rowp4, sedge4, (float*)d_out, NNODES,
        nullptr, nullptr, nullptr, nullptr, nullptr);
}